// Round 7
// baseline (2381.276 us; speedup 1.0000x reference)
//
#include <hip/hip_runtime.h>
#include <math.h>

// Problem constants
#define BB 64
#define SS 80
#define TT 20
#define FF 4096
#define HH 256
#define VV 32000

typedef __attribute__((ext_vector_type(8))) short bf16x8;
typedef __attribute__((ext_vector_type(4))) float f32x4;

__device__ __forceinline__ float fsig(float x){ return 1.f/(1.f+__expf(-x)); }
__device__ __forceinline__ float ftanh(float x){
    float xc = fminf(fmaxf(x,-15.f),15.f);
    float e = __expf(2.f*xc);
    return (e-1.f)/(e+1.f);
}
__device__ __forceinline__ unsigned int f2b(float x){
    unsigned int u = __float_as_uint(x);
    return (u + 0x7fffu + ((u>>16)&1u)) >> 16;
}
__device__ __forceinline__ float b2f(unsigned short u){
    return __uint_as_float(((unsigned)u)<<16);
}
// acc += dot2(bf16pair w, bf16pair h)  -- CDNA v_dot2_f32_bf16
__device__ __forceinline__ float dot2bf(unsigned w, unsigned hp, float acc){
    float r;
    asm("v_dot2_f32_bf16 %0, %1, %2, %3" : "=v"(r) : "v"(w), "v"(hp), "v"(acc));
    return r;
}
__device__ __forceinline__ void pack8(const float* __restrict__ s, unsigned short* __restrict__ d){
    float4 a = *reinterpret_cast<const float4*>(s);
    float4 b = *reinterpret_cast<const float4*>(s+4);
    uint4 o;
    o.x = f2b(a.x) | (f2b(a.y)<<16);
    o.y = f2b(a.z) | (f2b(a.w)<<16);
    o.z = f2b(b.x) | (f2b(b.y)<<16);
    o.w = f2b(b.z) | (f2b(b.w)<<16);
    *reinterpret_cast<uint4*>(d) = o;
}

// ---------------------------------------------------------------------------
// prep: packed bf16 recurrence weights, M3, bias sums, and all bf16 converts
// pk layout: pk[k2*Nj + j] = bf16 W[j][2k2] | bf16 W[j][2k2+1]<<16
// ---------------------------------------------------------------------------
__global__ __launch_bounds__(256) void prep_kernel(
    const float* __restrict__ eWhh0, const float* __restrict__ eWih1, const float* __restrict__ eWhh1,
    const float* __restrict__ dWih0, const float* __restrict__ dWhh0, const float* __restrict__ dWih1,
    const float* __restrict__ dWhh1, const float* __restrict__ attWs, const float* __restrict__ attWc,
    const float* __restrict__ cov_w, const float* __restrict__ cov_b,
    const float* __restrict__ e_bih0, const float* __restrict__ e_bhh0,
    const float* __restrict__ e_bih1, const float* __restrict__ e_bhh1,
    const float* __restrict__ d_bih0, const float* __restrict__ d_bhh0,
    const float* __restrict__ d_bih1, const float* __restrict__ d_bhh1,
    const float* __restrict__ W_out, const float* __restrict__ attWh,
    const float* __restrict__ W_vp,  const float* __restrict__ eWih0,
    const float* __restrict__ video, const float* __restrict__ emb,
    const int*   __restrict__ captions,
    unsigned* pkWhh0e, unsigned* pkWhh1e, unsigned* pkWx0d,
    unsigned* pkWhh0d, unsigned* pkWih1d, unsigned* pkWhh1d, unsigned* pkWs,
    float* M3, float* attcb,
    float* b0e, float* b1e, float* b0d, float* b1d,
    unsigned short* Wob, unsigned short* Wib1, unsigned short* Whb,
    unsigned short* Wvpb, unsigned short* Wih0b, unsigned short* dWx0b,
    unsigned short* embg, unsigned short* vidb)
{
    int blk = blockIdx.x, tid = threadIdx.x;
    if (blk < 1856){
        const float* src; int stride, coff, Nj, j0, k0; unsigned* dst;
        if (blk < 1792){
            int mat = blk >> 8, tl = blk & 255;
            switch(mat){
                case 0: src=eWhh0; stride=256; coff=0;   dst=pkWhh0e; break;
                case 1: src=eWhh1; stride=256; coff=0;   dst=pkWhh1e; break;
                case 2: src=dWih0; stride=512; coff=256; dst=pkWx0d;  break;  // ctx cols
                case 3: src=dWhh0; stride=256; coff=0;   dst=pkWhh0d; break;
                case 4: src=dWih1; stride=256; coff=0;   dst=pkWih1d; break;
                case 5: src=dWhh1; stride=256; coff=0;   dst=pkWhh1d; break;
                default: return;   // spare slot
            }
            Nj = 1024; j0 = (tl>>3)*32; k0 = (tl&7)*32;
        } else {
            int tl = blk - 1792;
            src=attWs; stride=256; coff=0; dst=pkWs;
            Nj = 256; j0 = (tl>>3)*32; k0 = (tl&7)*32;
        }
        __shared__ float t1[32][33];
        int r = tid >> 5, c = tid & 31;
        #pragma unroll
        for (int i=0;i<4;i++)
            t1[r+i*8][c] = src[(size_t)(j0+r+i*8)*stride + coff + k0 + c];
        __syncthreads();
        int k2l = tid >> 5, j = tid & 31;
        #pragma unroll
        for (int i=0;i<2;i++){
            int kq = k2l + i*8;
            dst[(size_t)(k0/2 + kq)*Nj + j0 + j] =
                f2b(t1[j][2*kq]) | (f2b(t1[j][2*kq+1])<<16);
        }
        return;
    }
    if (blk == 1856){
        float m0=0.f,m1=0.f,m2=0.f,cb=0.f;
        for (int c=0;c<64;c++){
            float w = attWc[tid*64+c];
            m0 += w*cov_w[c*3+0]; m1 += w*cov_w[c*3+1]; m2 += w*cov_w[c*3+2];
            cb += w*cov_b[c];
        }
        M3[tid*3+0]=m0; M3[tid*3+1]=m1; M3[tid*3+2]=m2; attcb[tid]=cb;
        return;
    }
    if (blk == 1857){
        for (int i=tid;i<1024;i+=256){
            b0e[i]=e_bih0[i]+e_bhh0[i]; b1e[i]=e_bih1[i]+e_bhh1[i];
            b0d[i]=d_bih0[i]+d_bhh0[i]; b1d[i]=d_bih1[i]+d_bhh1[i];
        }
        return;
    }
    // bf16 conversions, 2048 elems/block
    if (blk >= 6946){ size_t i=(size_t)(blk-6946)*2048 + tid*8; pack8(video+i, vidb+i); return; }
    if (blk >= 6786){ size_t i=(size_t)(blk-6786)*2048 + tid*8;
        int row = (int)(i>>8), col = (int)(i&255);
        pack8(emb + (size_t)captions[row]*256 + col, embg+i); return; }
    if (blk >= 6658){ size_t i=(size_t)(blk-6658)*2048 + tid*8;
        int j = (int)(i>>8), k = (int)(i&255);
        pack8(dWih0 + (size_t)j*512 + k, dWx0b+i); return; }
    if (blk >= 6530){ size_t i=(size_t)(blk-6530)*2048 + tid*8; pack8(eWih0+i, Wih0b+i); return; }
    if (blk >= 6018){ size_t i=(size_t)(blk-6018)*2048 + tid*8; pack8(W_vp+i, Wvpb+i); return; }
    if (blk >= 5986){ size_t i=(size_t)(blk-5986)*2048 + tid*8; pack8(attWh+i, Whb+i); return; }
    if (blk >= 5858){ size_t i=(size_t)(blk-5858)*2048 + tid*8; pack8(eWih1+i, Wib1+i); return; }
    { size_t i=(size_t)(blk-1858)*2048 + tid*8; pack8(W_out+i, Wob+i); }
}

// ---------------------------------------------------------------------------
// Generic bf16 MFMA GEMM: out[M,N] = A[M,K] @ B[N,K]^T (+bias)
// grid (N/64, M/64), 256 threads; wave = 16 m-rows x 64 n-cols
// ---------------------------------------------------------------------------
template<bool OUTBF>
__global__ __launch_bounds__(256) void gemm_bf16(int K, int N,
    const short* __restrict__ A, const short* __restrict__ Bw,
    const float* __restrict__ bias, void* __restrict__ out)
{
    int w = threadIdx.x >> 6, lane = threadIdx.x & 63;
    int m0 = blockIdx.y*64 + w*16, n0 = blockIdx.x*64;
    int row = lane & 15, kg = lane >> 4;
    const short* arow = A + (size_t)(m0 + row)*K + kg*8;
    f32x4 acc[4] = {};
    for (int kk=0; kk<K; kk+=32){
        bf16x8 a = *reinterpret_cast<const bf16x8*>(arow + kk);
        #pragma unroll
        for (int f=0; f<4; ++f){
            bf16x8 bfr = *reinterpret_cast<const bf16x8*>(
                Bw + (size_t)(n0 + f*16 + row)*K + kk + kg*8);
            acc[f] = __builtin_amdgcn_mfma_f32_16x16x32_bf16(a, bfr, acc[f], 0, 0, 0);
        }
    }
    #pragma unroll
    for (int f=0; f<4; ++f){
        int n = n0 + f*16 + row;
        float bv = bias ? bias[n] : 0.f;
        #pragma unroll
        for (int r=0; r<4; ++r){
            int m = m0 + kg*4 + r;
            float v = acc[f][r] + bv;
            if (OUTBF) ((unsigned short*)out)[(size_t)m*N + n] = (unsigned short)f2b(v);
            else       ((float*)out)[(size_t)m*N + n] = v;
        }
    }
}

// ---------------------------------------------------------------------------
// Weight-resident LSTM scan (encoder layers). 64 blocks, 512 threads.
// ---------------------------------------------------------------------------
__global__ __launch_bounds__(512, 2) void lstm_scan(
    int nsteps,
    const float* __restrict__ zx,
    const unsigned* __restrict__ pk,
    unsigned short* __restrict__ hseq,
    float* __restrict__ outf,
    unsigned short* __restrict__ hfin,
    float* __restrict__ cfin,
    int fin_off)
{
    __shared__ uint4 ws[1024][8];        // 128KB swizzled weight slice
    __shared__ uint4 hp4[32];            // 256 bf16 h as 32 uint4
    __shared__ float zsf[256], zso[256];
    int b = blockIdx.x, tid = threadIdx.x;
    int j0 = tid, j1 = tid + 512;
    unsigned wv0[96], wv1[96];
    #pragma unroll
    for (int kk=0; kk<96; kk++){
        wv0[kk] = pk[(size_t)kk*1024 + j0];
        wv1[kk] = pk[(size_t)kk*1024 + j1];
    }
    unsigned* wsu = (unsigned*)ws;
    for (int i = tid; i < 32*1024; i += 512){
        int kk = i >> 10, j = i & 1023;
        wsu[j*32 + (((kk>>2) ^ (j&7))<<2) + (kk&3)] = pk[(size_t)(96+kk)*1024 + j];
    }
    float c = 0.f;
    if (tid < 128) ((unsigned*)hp4)[tid] = 0;
    __syncthreads();
    int p0 = j0 & 7, p1 = j1 & 7;
    for (int t=0; t<nsteps; ++t){
        size_t row = (size_t)b*nsteps + t;
        float zxv0=0.f, zxv1=0.f, zxv2=0.f, zxv3=0.f;
        if (tid < 256){
            const float* zr = zx + row*1024;
            zxv0=zr[tid]; zxv1=zr[tid+256]; zxv2=zr[tid+512]; zxv3=zr[tid+768];
        }
        float a0=0.f,a1=0.f,a2=0.f,a3=0.f;
        #pragma unroll
        for (int g=0; g<24; g++){
            uint4 hc = hp4[g];
            a0=dot2bf(wv0[4*g+0],hc.x,a0); a1=dot2bf(wv1[4*g+0],hc.x,a1);
            a2=dot2bf(wv0[4*g+1],hc.y,a2); a3=dot2bf(wv1[4*g+1],hc.y,a3);
            a0=dot2bf(wv0[4*g+2],hc.z,a0); a1=dot2bf(wv1[4*g+2],hc.z,a1);
            a2=dot2bf(wv0[4*g+3],hc.w,a2); a3=dot2bf(wv1[4*g+3],hc.w,a3);
        }
        #pragma unroll
        for (int g=0; g<8; g++){
            uint4 hc = hp4[24+g];
            uint4 w0 = ws[j0][g ^ p0];
            uint4 w1 = ws[j1][g ^ p1];
            a0=dot2bf(w0.x,hc.x,a0); a1=dot2bf(w1.x,hc.x,a1);
            a2=dot2bf(w0.y,hc.y,a2); a3=dot2bf(w1.y,hc.y,a3);
            a0=dot2bf(w0.z,hc.z,a0); a1=dot2bf(w1.z,hc.z,a1);
            a2=dot2bf(w0.w,hc.w,a2); a3=dot2bf(w1.w,hc.w,a3);
        }
        if (tid >= 256){ zsf[tid-256] = a0+a2; zso[tid-256] = a1+a3; }
        __syncthreads();
        if (tid < 256){
            float i_ = zxv0 + a0+a2;
            float f_ = zxv1 + zsf[tid];
            float g_ = zxv2 + a1+a3;
            float o_ = zxv3 + zso[tid];
            float cn = fsig(f_)*c + fsig(i_)*ftanh(g_);
            c = cn;
            float hn = fsig(o_)*ftanh(cn);
            unsigned short hb = (unsigned short)f2b(hn);
            ((unsigned short*)hp4)[tid] = hb;
            hseq[row*256 + tid] = hb;
            if (outf) outf[row*256 + tid] = hn;
        }
        __syncthreads();
    }
    if (tid < 256){
        hfin[b*512 + fin_off + tid] = ((unsigned short*)hp4)[tid];
        cfin[b*512 + fin_off + tid] = c;
    }
}

// ---------------------------------------------------------------------------
// dot phase: thread computes 4 outputs (j=jq*4..+3) over ITERS k-pairs
// ---------------------------------------------------------------------------
template<int ITERS>
__device__ __forceinline__ void dot_phase(const unsigned* __restrict__ wbase,
    const unsigned* __restrict__ hu, int k2base, int jq, float* __restrict__ zrow)
{
    float a0=0.f,a1=0.f,a2=0.f,a3=0.f;
    const uint4* wp = (const uint4*)(wbase + (size_t)k2base*1024 + jq*4);
    #pragma unroll 8
    for (int kk=0; kk<ITERS; ++kk){
        uint4 w = wp[(size_t)kk*256];
        unsigned hp = hu[k2base+kk];
        a0=dot2bf(w.x,hp,a0); a1=dot2bf(w.y,hp,a1);
        a2=dot2bf(w.z,hp,a2); a3=dot2bf(w.w,hp,a3);
    }
    zrow[jq*4+0]=a0; zrow[jq*4+1]=a1; zrow[jq*4+2]=a2; zrow[jq*4+3]=a3;
}

// lstm prefetch chunk: runtime bounds, unroll 8
__device__ __forceinline__ void lch(int A, int B2, const uint4* __restrict__ wp,
    const unsigned* __restrict__ hu, float& a0, float& a1, float& a2, float& a3)
{
    #pragma unroll 8
    for (int k2=A; k2<B2; ++k2){
        uint4 w = wp[(size_t)k2*256];
        unsigned hp = hu[k2];
        a0=dot2bf(w.x,hp,a0); a1=dot2bf(w.y,hp,a1);
        a2=dot2bf(w.z,hp,a2); a3=dot2bf(w.w,hp,a3);
    }
}

// ---------------------------------------------------------------------------
// Decoder scan: 64 blocks (1/batch), 1024 threads.
// Waves 0-7: attention pipeline.  Waves 8-15 (concurrently): stream+compute
// whh0@h1[t-1] and whh1@h2[t-1] (the weight traffic overlaps attention).
// Then all threads: wx0@ctx -> pointwise0 -> wih1@h1 -> pointwise1 + LN.
// ---------------------------------------------------------------------------
__global__ __launch_bounds__(1024) void dec_scan(
    const float* __restrict__ embproj,
    const unsigned* __restrict__ wx0, const unsigned* __restrict__ whh0,
    const unsigned* __restrict__ wih1, const unsigned* __restrict__ whh1,
    const unsigned* __restrict__ pkWs,
    const float* __restrict__ b1d,
    const unsigned short* __restrict__ encp,  // [5120][256] bf16
    const unsigned short* __restrict__ enco,  // [5120][256] bf16 (= h2seq)
    const float* __restrict__ att_v, const float* __restrict__ M3,
    const float* __restrict__ attcb,
    const float* __restrict__ ln_g, const float* __restrict__ ln_b,
    const float* __restrict__ encfC, const unsigned short* __restrict__ encfH,
    unsigned short* __restrict__ normedb)
{
    int b = blockIdx.x, tid = threadIdx.x;
    __shared__ unsigned short encpL[SS*256];   // 40KB
    __shared__ unsigned short encoL[SS*256];   // 40KB
    __shared__ unsigned short h1b[256], h2b[256], ctxb[256];
    __shared__ float c1s[256], c2s[256];
    __shared__ float zb[4][1024];
    __shared__ float zbA[1024], zbB[1024];
    __shared__ float covs[82], scs[80], attns[80], dps[256];
    __shared__ float red[16];
    {
        const uint4* sp = (const uint4*)(encp + (size_t)b*SS*256);
        const uint4* so = (const uint4*)(enco + (size_t)b*SS*256);
        uint4* dp = (uint4*)encpL;
        uint4* dq = (uint4*)encoL;
        for (int i=tid; i<SS*256/8; i+=1024){ dp[i] = sp[i]; dq[i] = so[i]; }
    }
    int h = tid & 255;
    float bz0=0.f,bz1=0.f,bz2=0.f,bz3=0.f, gg=0.f, bb2=0.f;
    if (tid < 256){
        h1b[tid] = encfH[b*512 + tid];
        h2b[tid] = encfH[b*512 + 256 + tid];
        c1s[tid] = encfC[b*512 + tid];
        c2s[tid] = encfC[b*512 + 256 + tid];
        bz0=b1d[tid]; bz1=b1d[tid+256]; bz2=b1d[tid+512]; bz3=b1d[tid+768];
        gg=ln_g[tid]; bb2=ln_b[tid];
    }
    if (tid < 82) covs[tid] = 0.f;
    int wv = tid >> 6, lane = tid & 63;
    float va[4], m30[4], m31[4], m32[4];
    #pragma unroll
    for (int i=0;i<4;i++){
        int hh = lane + i*64;
        va[i]=att_v[hh]; m30[i]=M3[hh*3]; m31[i]=M3[hh*3+1]; m32[i]=M3[hh*3+2];
    }
    const unsigned* h1u = (const unsigned*)h1b;
    const unsigned* h2u = (const unsigned*)h2b;
    const unsigned* cxu = (const unsigned*)ctxb;
    // role split
    int hi  = tid >> 9;                 // 0: attention waves, 1: lstm-prefetch waves
    int q   = (tid >> 8) & 1;           // low-group 2-way split index
    int ljq = tid & 255;                // high-group output quad
    int lm  = (tid >> 8) & 1;           // high-group matrix select
    const uint4* lwp = (const uint4*)(lm ? whh1 : whh0) + ljq;
    const unsigned* lhu = lm ? h2u : h1u;
    float* lzb = lm ? zbB : zbA;
    __syncthreads();
    for (int t=0; t<TT; ++t){
        float la0=0.f,la1=0.f,la2=0.f,la3=0.f;
        float ep0=0.f,ep1=0.f,ep2=0.f,ep3=0.f;
        // ---- overlapped region: attention (low) || whh0/whh1 stream (high) ----
        // chunk 0: dec_proj partials | lstm 0..25
        if (hi) lch(0, 26, lwp, lhu, la0,la1,la2,la3);
        else {
            if (tid < 256){
                const float* er = embproj + ((size_t)b*TT + t)*1024;
                ep0=er[h]; ep1=er[h+256]; ep2=er[h+512]; ep3=er[h+768];
            }
            float acc = 0.f;
            const unsigned* wp = pkWs + (size_t)(q*64)*256 + h;
            #pragma unroll 8
            for (int kk=0; kk<64; ++kk)
                acc = dot2bf(wp[(size_t)kk*256], h2u[q*64+kk], acc);
            zb[q][h] = acc;
        }
        __syncthreads();
        // chunk 1: dps reduce | lstm 26..51
        if (hi) lch(26, 52, lwp, lhu, la0,la1,la2,la3);
        else if (tid < 256) dps[tid] = attcb[tid] + zb[0][tid] + zb[1][tid];
        __syncthreads();
        // chunk 2: scores | lstm 52..77
        if (hi) lch(52, 78, lwp, lhu, la0,la1,la2,la3);
        else {
            for (int s = wv*10; s < wv*10+10; ++s){
                float c0=covs[s], c1v=covs[s+1], c2v=covs[s+2];
                float p = 0.f;
                #pragma unroll
                for (int i=0;i<4;i++){
                    int hh = lane + i*64;
                    float e = b2f(encpL[s*256+hh]) + dps[hh]
                            + m30[i]*c0 + m31[i]*c1v + m32[i]*c2v;
                    p += va[i]*ftanh(e);
                }
                #pragma unroll
                for (int off=32;off;off>>=1) p += __shfl_down(p, off);
                if (lane == 0) scs[s] = p;
            }
        }
        __syncthreads();
        // chunk 3: softmax | lstm 78..103
        if (hi) lch(78, 104, lwp, lhu, la0,la1,la2,la3);
        else if (tid < 64){
            float a = scs[tid];
            float bsc = (tid < 16) ? scs[tid+64] : -3.4e38f;
            float mx = fmaxf(a, bsc);
            #pragma unroll
            for (int off=32;off;off>>=1) mx = fmaxf(mx, __shfl_xor(mx, off));
            float ea = __expf(a - mx);
            float eb = (tid < 16) ? __expf(bsc - mx) : 0.f;
            float sum = ea + eb;
            #pragma unroll
            for (int off=32;off;off>>=1) sum += __shfl_xor(sum, off);
            float inv = 1.f/sum;
            attns[tid] = ea*inv;
            if (tid < 16) attns[tid+64] = eb*inv;
        }
        __syncthreads();
        // chunk 4: cov update + ctx partials | lstm 104..127 + store partials
        if (hi){
            lch(104, 128, lwp, lhu, la0,la1,la2,la3);
            lzb[ljq*4+0]=la0; lzb[ljq*4+1]=la1; lzb[ljq*4+2]=la2; lzb[ljq*4+3]=la3;
        } else {
            if (tid < 80) covs[tid+1] += attns[tid];
            float acc = 0.f;
            for (int s=q*40; s<q*40+40; ++s)
                acc += attns[s]*b2f(encoL[s*256 + h]);
            zb[q][h] = acc;
        }
        __syncthreads();
        if (tid < 256)
            ctxb[h] = (unsigned short)f2b(zb[0][h] + zb[1][h]);
        __syncthreads();
        // ---- lstm0 sequential part: wx0 @ ctx (4-way k-split) ----
        dot_phase<32>(wx0, cxu, (tid>>8)*32, tid&255, &zb[tid>>8][0]);
        __syncthreads();
        if (tid < 256){
            float i_ = ep0 + zb[0][h]+zb[1][h]+zb[2][h]+zb[3][h] + zbA[h];
            float f_ = ep1 + zb[0][h+256]+zb[1][h+256]+zb[2][h+256]+zb[3][h+256] + zbA[h+256];
            float g_ = ep2 + zb[0][h+512]+zb[1][h+512]+zb[2][h+512]+zb[3][h+512] + zbA[h+512];
            float o_ = ep3 + zb[0][h+768]+zb[1][h+768]+zb[2][h+768]+zb[3][h+768] + zbA[h+768];
            float cn = fsig(f_)*c1s[h] + fsig(i_)*ftanh(g_);
            c1s[h] = cn;
            h1b[h] = (unsigned short)f2b(fsig(o_)*ftanh(cn));
        }
        __syncthreads();
        // ---- lstm1 sequential part: wih1 @ h1[t] (4-way k-split) ----
        dot_phase<32>(wih1, h1u, (tid>>8)*32, tid&255, &zb[tid>>8][0]);
        __syncthreads();
        float hn = 0.f;
        if (tid < 256){
            float i_ = bz0 + zb[0][h]+zb[1][h]+zb[2][h]+zb[3][h] + zbB[h];
            float f_ = bz1 + zb[0][h+256]+zb[1][h+256]+zb[2][h+256]+zb[3][h+256] + zbB[h+256];
            float g_ = bz2 + zb[0][h+512]+zb[1][h+512]+zb[2][h+512]+zb[3][h+512] + zbB[h+512];
            float o_ = bz3 + zb[0][h+768]+zb[1][h+768]+zb[2][h+768]+zb[3][h+768] + zbB[h+768];
            float cn = fsig(f_)*c2s[h] + fsig(i_)*ftanh(g_);
            c2s[h] = cn;
            hn = fsig(o_)*ftanh(cn);
            h2b[h] = (unsigned short)f2b(hn);
        }
        // fused LayerNorm over h2
        float s1 = hn;
        #pragma unroll
        for (int off=32;off;off>>=1) s1 += __shfl_xor(s1, off);
        if (lane == 0) red[wv] = s1;
        __syncthreads();
        float mean = (red[0]+red[1]+red[2]+red[3]) * (1.f/256.f);
        __syncthreads();
        float d = (tid < 256) ? (hn - mean) : 0.f;
        float s2 = d*d;
        #pragma unroll
        for (int off=32;off;off>>=1) s2 += __shfl_xor(s2, off);
        if (lane == 0) red[wv] = s2;
        __syncthreads();
        float var = (red[0]+red[1]+red[2]+red[3]) * (1.f/256.f);
        if (tid < 256)
            normedb[((size_t)b*TT + t)*256 + h] =
                (unsigned short)f2b(d*rsqrtf(var + 1e-5f)*gg + bb2);
        __syncthreads();
    }
}

// ---------------------------------------------------------------------------
// Logits: bf16 MFMA, W-stationary. Block = 64 n-cols; loops all 80 m-tiles.
// ---------------------------------------------------------------------------
__global__ __launch_bounds__(256) void logits_mfma(
    const short* __restrict__ A, const short* __restrict__ Bw,
    const float* __restrict__ bias, float* __restrict__ out)
{
    int w = threadIdx.x >> 6, lane = threadIdx.x & 63;
    int n0 = blockIdx.x*64 + w*16;
    int row = lane & 15, kg = lane >> 4;
    bf16x8 bfr[8];
    const short* brow = Bw + (size_t)(n0 + row)*256 + kg*8;
    #pragma unroll
    for (int kk=0;kk<8;kk++) bfr[kk] = *reinterpret_cast<const bf16x8*>(brow + kk*32);
    float bv = bias[n0 + row];
    for (int mt=0; mt<80; ++mt){
        int m0 = mt*16;
        const short* arow = A + (size_t)(m0 + row)*256 + kg*8;
        f32x4 acc = {};
        #pragma unroll
        for (int kk=0;kk<8;kk++){
            bf16x8 a = *reinterpret_cast<const bf16x8*>(arow + kk*32);
            acc = __builtin_amdgcn_mfma_f32_16x16x32_bf16(a, bfr[kk], acc, 0, 0, 0);
        }
        #pragma unroll
        for (int r=0;r<4;r++){
            int m = m0 + kg*4 + r;
            out[(size_t)m*VV + n0 + row] = acc[r] + bv;
        }
    }
}

// ---------------------------------------------------------------------------
extern "C" void kernel_launch(void* const* d_in, const int* in_sizes, int n_in,
                              void* d_out, int out_size, void* d_ws, size_t ws_size,
                              hipStream_t stream)
{
    const float* video  = (const float*)d_in[0];
    const int*   caps   = (const int*)  d_in[1];
    const float* W_vp   = (const float*)d_in[2];
    const float* b_vp   = (const float*)d_in[3];
    const float* eWih0  = (const float*)d_in[4];
    const float* eWhh0  = (const float*)d_in[5];
    const float* e_bih0 = (const float*)d_in[6];
    const float* e_bhh0 = (const float*)d_in[7];
    const float* eWih1  = (const float*)d_in[8];
    const float* eWhh1  = (const float*)d_in[9];
    const float* e_bih1 = (const float*)d_in[10];
    const float* e_bhh1 = (const float*)d_in[11];
    const float* emb    = (const float*)d_in[12];
    const float* dWih0  = (const float*)d_in[13];
    const float* dWhh0  = (const float*)d_in[14];
    const float* d_bih0 = (const float*)d_in[15];
    const float* d_bhh0 = (const float*)d_in[16];
    const float* dWih1  = (const float*)d_in[17];
    const float* dWhh1  = (const float*)d_in[18];
    const float* d_bih1 = (const float*)d_in[19];
    const float* d_bhh1 = (const float*)d_in[20];
    const float* attWh  = (const float*)d_in[21];
    const float* attWs  = (const float*)d_in[22];
    const float* att_v  = (const float*)d_in[23];
    const float* attWc  = (const float*)d_in[24];
    const float* cov_w  = (const float*)d_in[25];
    const float* cov_b  = (const float*)d_in[26];
    const float* ln_g   = (const float*)d_in[27];
    const float* ln_b   = (const float*)d_in[28];
    const float* W_out  = (const float*)d_in[29];
    const float* b_out  = (const float*)d_in[30];
    float* out = (float*)d_out;

    float* W = (float*)d_ws;
    size_t o = 0;
    auto alloc = [&](size_t n){ size_t r = o; o += ((n + 63)/64)*64; return r; };

    // U region: vidb (bf16, 41.9MB) early, reused as z1x (fp32, 21MB) later
    float* U = W + alloc((size_t)10485760);
    unsigned short* vidb = (unsigned short*)U;
    float* z1x = U;
    float* zx0     = W + alloc((size_t)SS*BB*1024);     // fp32 [(b*80+t)*1024]
    float* embproj = W + alloc((size_t)TT*BB*1024);     // fp32 [(b*20+t)*1024]
    unsigned short* vp_b  = (unsigned short*)(W + alloc((size_t)SS*BB*HH/2));
    unsigned short* embg  = (unsigned short*)(W + alloc((size_t)TT*BB*HH/2));
    unsigned short* encpb = (unsigned short*)(W + alloc((size_t)BB*SS*HH/2));
    unsigned short* normedb = (unsigned short*)(W + alloc((size_t)BB*TT*HH/2));
    unsigned short* h1seq = (unsigned short*)(W + alloc((size_t)SS*BB*HH/2));
    unsigned short* h2seq = (unsigned short*)(W + alloc((size_t)SS*BB*HH/2));
    float* encfC   = W + alloc(BB*512);
    unsigned short* encfH = (unsigned short*)(W + alloc(BB*256));
    unsigned* pkWhh0e = (unsigned*)(W + alloc(128*1024));
    unsigned* pkWhh1e = (unsigned*)(W + alloc(128*1024));
    unsigned* pkWx0d  = (unsigned*)(W + alloc(128*1024));
    unsigned* pkWhh0d = (unsigned*)(W + alloc(128*1024));
    unsigned* pkWih1d = (unsigned*)(W + alloc(128*1024));
    unsigned* pkWhh1d = (unsigned*)(W + alloc(128*1024));
    unsigned* pkWs    = (unsigned*)(W + alloc(128*256));
    float* M3      = W + alloc(768);
    float* attcb   = W + alloc(256);
    float* b0e     = W + alloc(1024);
    float* b1e     = W + alloc(1024);
    float* b0d     = W + alloc(1024);
    float* b1d     = W + alloc(1024);
    unsigned short* Wob   = (unsigned short*)(W + alloc((size_t)VV*HH/2));
    unsigned short* Wib1  = (unsigned short*)(W + alloc(1024*HH/2));
    unsigned short* Whb   = (unsigned short*)(W + alloc(256*HH/2));
    unsigned short* Wvpb  = (unsigned short*)(W + alloc((size_t)HH*FF/2));
    unsigned short* Wih0b = (unsigned short*)(W + alloc(1024*HH/2));
    unsigned short* dWx0b = (unsigned short*)(W + alloc(1024*HH/2));
    (void)ws_size; (void)n_in; (void)in_sizes; (void)out_size;

    prep_kernel<<<17186, 256, 0, stream>>>(
        eWhh0, eWih1, eWhh1, dWih0, dWhh0, dWih1, dWhh1, attWs, attWc,
        cov_w, cov_b, e_bih0, e_bhh0, e_bih1, e_bhh1, d_bih0, d_bhh0, d_bih1, d_bhh1,
        W_out, attWh, W_vp, eWih0, video, emb, caps,
        pkWhh0e, pkWhh1e, pkWx0d, pkWhh0d, pkWih1d, pkWhh1d, pkWs,
        M3, attcb, b0e, b1e, b0d, b1d,
        Wob, Wib1, Whb, Wvpb, Wih0b, dWx0b, embg, vidb);

    // vp_b = bf16(video @ W_vp^T + b_vp)   (5120x256, K=4096)
    gemm_bf16<true><<<dim3(4, 80), 256, 0, stream>>>(
        FF, HH, (const short*)vidb, (const short*)Wvpb, b_vp, vp_b);

    // zx0 = vp_b @ eWih0^T + (bih0+bhh0)   (5120x1024, K=256) fp32
    gemm_bf16<false><<<dim3(16, 80), 256, 0, stream>>>(
        HH, 1024, (const short*)vp_b, (const short*)Wih0b, b0e, zx0);

    // embproj = embg @ dWih0[:, :256]^T + (bih0+bhh0)  (1280x1024, K=256) fp32
    gemm_bf16<false><<<dim3(16, 20), 256, 0, stream>>>(
        HH, 1024, (const short*)embg, (const short*)dWx0b, b0d, embproj);

    // encoder layer0 scan (weight-resident)
    lstm_scan<<<64, 512, 0, stream>>>(SS, zx0, pkWhh0e, h1seq, nullptr,
                                      encfH, encfC, 0);

    // z1x = h1seq @ Wih1^T + b1e  (5120x1024, K=256) fp32 (reuses U)
    gemm_bf16<false><<<dim3(16, 80), 256, 0, stream>>>(
        HH, 1024, (const short*)h1seq, (const short*)Wib1, b1e, z1x);

    // encoder layer1 scan; h2seq bf16 doubles as enco
    lstm_scan<<<64, 512, 0, stream>>>(SS, z1x, pkWhh1e, h2seq, nullptr,
                                      encfH, encfC, 256);

    // encp = bf16(h2seq @ attWh^T)  (5120x256, K=256)
    gemm_bf16<true><<<dim3(4, 80), 256, 0, stream>>>(
        HH, HH, (const short*)h2seq, (const short*)Whb, nullptr, encpb);

    // decoder scan (attention-overlapped weight streaming)
    dec_scan<<<64, 1024, 0, stream>>>(embproj, pkWx0d, pkWhh0d, pkWih1d, pkWhh1d,
                                      pkWs, b1d, encpb, h2seq, att_v, M3, attcb,
                                      ln_g, ln_b, encfC, encfH, normedb);

    // logits = normed @ W_out^T + b_out  (1280 x 32000, K=256)
    logits_mfma<<<VV/64, 256, 0, stream>>>(
        (const short*)normedb, (const short*)Wob, b_out, out);
}

// Round 8
// 2364.809 us; speedup vs baseline: 1.0070x; 1.0070x over previous
//
#include <hip/hip_runtime.h>
#include <math.h>

// Problem constants
#define BB 64
#define SS 80
#define TT 20
#define FF 4096
#define HH 256
#define VV 32000

typedef __attribute__((ext_vector_type(8))) short bf16x8;
typedef __attribute__((ext_vector_type(4))) float f32x4;

__device__ __forceinline__ float fsig(float x){ return 1.f/(1.f+__expf(-x)); }
__device__ __forceinline__ float ftanh(float x){
    float xc = fminf(fmaxf(x,-15.f),15.f);
    float e = __expf(2.f*xc);
    return (e-1.f)/(e+1.f);
}
__device__ __forceinline__ unsigned int f2b(float x){
    unsigned int u = __float_as_uint(x);
    return (u + 0x7fffu + ((u>>16)&1u)) >> 16;
}
__device__ __forceinline__ float b2f(unsigned short u){
    return __uint_as_float(((unsigned)u)<<16);
}
// acc += dot2(bf16pair w, bf16pair h)  -- CDNA v_dot2_f32_bf16
__device__ __forceinline__ float dot2bf(unsigned w, unsigned hp, float acc){
    float r;
    asm("v_dot2_f32_bf16 %0, %1, %2, %3" : "=v"(r) : "v"(w), "v"(hp), "v"(acc));
    return r;
}
__device__ __forceinline__ void pack8(const float* __restrict__ s, unsigned short* __restrict__ d){
    float4 a = *reinterpret_cast<const float4*>(s);
    float4 b = *reinterpret_cast<const float4*>(s+4);
    uint4 o;
    o.x = f2b(a.x) | (f2b(a.y)<<16);
    o.y = f2b(a.z) | (f2b(a.w)<<16);
    o.z = f2b(b.x) | (f2b(b.y)<<16);
    o.w = f2b(b.z) | (f2b(b.w)<<16);
    *reinterpret_cast<uint4*>(d) = o;
}

// ---------------------------------------------------------------------------
// prep: packed bf16 recurrence weights, M3, bias sums, and all bf16 converts
// pk layout: pk[k2*Nj + j] = bf16 W[j][2k2] | bf16 W[j][2k2+1]<<16
// ---------------------------------------------------------------------------
__global__ __launch_bounds__(256) void prep_kernel(
    const float* __restrict__ eWhh0, const float* __restrict__ eWih1, const float* __restrict__ eWhh1,
    const float* __restrict__ dWih0, const float* __restrict__ dWhh0, const float* __restrict__ dWih1,
    const float* __restrict__ dWhh1, const float* __restrict__ attWs, const float* __restrict__ attWc,
    const float* __restrict__ cov_w, const float* __restrict__ cov_b,
    const float* __restrict__ e_bih0, const float* __restrict__ e_bhh0,
    const float* __restrict__ e_bih1, const float* __restrict__ e_bhh1,
    const float* __restrict__ d_bih0, const float* __restrict__ d_bhh0,
    const float* __restrict__ d_bih1, const float* __restrict__ d_bhh1,
    const float* __restrict__ W_out, const float* __restrict__ attWh,
    const float* __restrict__ W_vp,  const float* __restrict__ eWih0,
    const float* __restrict__ video, const float* __restrict__ emb,
    const int*   __restrict__ captions,
    unsigned* pkWhh0e, unsigned* pkWhh1e, unsigned* pkWx0d,
    unsigned* pkWhh0d, unsigned* pkWih1d, unsigned* pkWhh1d, unsigned* pkWs,
    float* M3, float* attcb,
    float* b0e, float* b1e, float* b0d, float* b1d,
    unsigned short* Wob, unsigned short* Wib1, unsigned short* Whb,
    unsigned short* Wvpb, unsigned short* Wih0b, unsigned short* dWx0b,
    unsigned short* embg, unsigned short* vidb)
{
    int blk = blockIdx.x, tid = threadIdx.x;
    if (blk < 1856){
        const float* src; int stride, coff, Nj, j0, k0; unsigned* dst;
        if (blk < 1792){
            int mat = blk >> 8, tl = blk & 255;
            switch(mat){
                case 0: src=eWhh0; stride=256; coff=0;   dst=pkWhh0e; break;
                case 1: src=eWhh1; stride=256; coff=0;   dst=pkWhh1e; break;
                case 2: src=dWih0; stride=512; coff=256; dst=pkWx0d;  break;  // ctx cols
                case 3: src=dWhh0; stride=256; coff=0;   dst=pkWhh0d; break;
                case 4: src=dWih1; stride=256; coff=0;   dst=pkWih1d; break;
                case 5: src=dWhh1; stride=256; coff=0;   dst=pkWhh1d; break;
                default: return;   // spare slot
            }
            Nj = 1024; j0 = (tl>>3)*32; k0 = (tl&7)*32;
        } else {
            int tl = blk - 1792;
            src=attWs; stride=256; coff=0; dst=pkWs;
            Nj = 256; j0 = (tl>>3)*32; k0 = (tl&7)*32;
        }
        __shared__ float t1[32][33];
        int r = tid >> 5, c = tid & 31;
        #pragma unroll
        for (int i=0;i<4;i++)
            t1[r+i*8][c] = src[(size_t)(j0+r+i*8)*stride + coff + k0 + c];
        __syncthreads();
        int k2l = tid >> 5, j = tid & 31;
        #pragma unroll
        for (int i=0;i<2;i++){
            int kq = k2l + i*8;
            dst[(size_t)(k0/2 + kq)*Nj + j0 + j] =
                f2b(t1[j][2*kq]) | (f2b(t1[j][2*kq+1])<<16);
        }
        return;
    }
    if (blk == 1856){
        float m0=0.f,m1=0.f,m2=0.f,cb=0.f;
        for (int c=0;c<64;c++){
            float w = attWc[tid*64+c];
            m0 += w*cov_w[c*3+0]; m1 += w*cov_w[c*3+1]; m2 += w*cov_w[c*3+2];
            cb += w*cov_b[c];
        }
        M3[tid*3+0]=m0; M3[tid*3+1]=m1; M3[tid*3+2]=m2; attcb[tid]=cb;
        return;
    }
    if (blk == 1857){
        for (int i=tid;i<1024;i+=256){
            b0e[i]=e_bih0[i]+e_bhh0[i]; b1e[i]=e_bih1[i]+e_bhh1[i];
            b0d[i]=d_bih0[i]+d_bhh0[i]; b1d[i]=d_bih1[i]+d_bhh1[i];
        }
        return;
    }
    // bf16 conversions, 2048 elems/block
    if (blk >= 6946){ size_t i=(size_t)(blk-6946)*2048 + tid*8; pack8(video+i, vidb+i); return; }
    if (blk >= 6786){ size_t i=(size_t)(blk-6786)*2048 + tid*8;
        int row = (int)(i>>8), col = (int)(i&255);
        pack8(emb + (size_t)captions[row]*256 + col, embg+i); return; }
    if (blk >= 6658){ size_t i=(size_t)(blk-6658)*2048 + tid*8;
        int j = (int)(i>>8), k = (int)(i&255);
        pack8(dWih0 + (size_t)j*512 + k, dWx0b+i); return; }
    if (blk >= 6530){ size_t i=(size_t)(blk-6530)*2048 + tid*8; pack8(eWih0+i, Wih0b+i); return; }
    if (blk >= 6018){ size_t i=(size_t)(blk-6018)*2048 + tid*8; pack8(W_vp+i, Wvpb+i); return; }
    if (blk >= 5986){ size_t i=(size_t)(blk-5986)*2048 + tid*8; pack8(attWh+i, Whb+i); return; }
    if (blk >= 5858){ size_t i=(size_t)(blk-5858)*2048 + tid*8; pack8(eWih1+i, Wib1+i); return; }
    { size_t i=(size_t)(blk-1858)*2048 + tid*8; pack8(W_out+i, Wob+i); }
}

// ---------------------------------------------------------------------------
// Generic bf16 MFMA GEMM: out[M,N] = A[M,K] @ B[N,K]^T (+bias)
// grid (N/64, M/64), 256 threads; wave = 16 m-rows x 64 n-cols
// ---------------------------------------------------------------------------
template<bool OUTBF>
__global__ __launch_bounds__(256) void gemm_bf16(int K, int N,
    const short* __restrict__ A, const short* __restrict__ Bw,
    const float* __restrict__ bias, void* __restrict__ out)
{
    int w = threadIdx.x >> 6, lane = threadIdx.x & 63;
    int m0 = blockIdx.y*64 + w*16, n0 = blockIdx.x*64;
    int row = lane & 15, kg = lane >> 4;
    const short* arow = A + (size_t)(m0 + row)*K + kg*8;
    f32x4 acc[4] = {};
    for (int kk=0; kk<K; kk+=32){
        bf16x8 a = *reinterpret_cast<const bf16x8*>(arow + kk);
        #pragma unroll
        for (int f=0; f<4; ++f){
            bf16x8 bfr = *reinterpret_cast<const bf16x8*>(
                Bw + (size_t)(n0 + f*16 + row)*K + kk + kg*8);
            acc[f] = __builtin_amdgcn_mfma_f32_16x16x32_bf16(a, bfr, acc[f], 0, 0, 0);
        }
    }
    #pragma unroll
    for (int f=0; f<4; ++f){
        int n = n0 + f*16 + row;
        float bv = bias ? bias[n] : 0.f;
        #pragma unroll
        for (int r=0; r<4; ++r){
            int m = m0 + kg*4 + r;
            float v = acc[f][r] + bv;
            if (OUTBF) ((unsigned short*)out)[(size_t)m*N + n] = (unsigned short)f2b(v);
            else       ((float*)out)[(size_t)m*N + n] = v;
        }
    }
}

// ---------------------------------------------------------------------------
// Weight-resident LSTM scan (encoder layers). 64 blocks, 512 threads.
// ---------------------------------------------------------------------------
__global__ __launch_bounds__(512, 2) void lstm_scan(
    int nsteps,
    const float* __restrict__ zx,
    const unsigned* __restrict__ pk,
    unsigned short* __restrict__ hseq,
    float* __restrict__ outf,
    unsigned short* __restrict__ hfin,
    float* __restrict__ cfin,
    int fin_off)
{
    __shared__ uint4 ws[1024][8];        // 128KB swizzled weight slice
    __shared__ uint4 hp4[32];            // 256 bf16 h as 32 uint4
    __shared__ float zsf[256], zso[256];
    int b = blockIdx.x, tid = threadIdx.x;
    int j0 = tid, j1 = tid + 512;
    unsigned wv0[96], wv1[96];
    #pragma unroll
    for (int kk=0; kk<96; kk++){
        wv0[kk] = pk[(size_t)kk*1024 + j0];
        wv1[kk] = pk[(size_t)kk*1024 + j1];
    }
    unsigned* wsu = (unsigned*)ws;
    for (int i = tid; i < 32*1024; i += 512){
        int kk = i >> 10, j = i & 1023;
        wsu[j*32 + (((kk>>2) ^ (j&7))<<2) + (kk&3)] = pk[(size_t)(96+kk)*1024 + j];
    }
    float c = 0.f;
    if (tid < 128) ((unsigned*)hp4)[tid] = 0;
    __syncthreads();
    int p0 = j0 & 7, p1 = j1 & 7;
    for (int t=0; t<nsteps; ++t){
        size_t row = (size_t)b*nsteps + t;
        float zxv0=0.f, zxv1=0.f, zxv2=0.f, zxv3=0.f;
        if (tid < 256){
            const float* zr = zx + row*1024;
            zxv0=zr[tid]; zxv1=zr[tid+256]; zxv2=zr[tid+512]; zxv3=zr[tid+768];
        }
        float a0=0.f,a1=0.f,a2=0.f,a3=0.f;
        #pragma unroll
        for (int g=0; g<24; g++){
            uint4 hc = hp4[g];
            a0=dot2bf(wv0[4*g+0],hc.x,a0); a1=dot2bf(wv1[4*g+0],hc.x,a1);
            a2=dot2bf(wv0[4*g+1],hc.y,a2); a3=dot2bf(wv1[4*g+1],hc.y,a3);
            a0=dot2bf(wv0[4*g+2],hc.z,a0); a1=dot2bf(wv1[4*g+2],hc.z,a1);
            a2=dot2bf(wv0[4*g+3],hc.w,a2); a3=dot2bf(wv1[4*g+3],hc.w,a3);
        }
        #pragma unroll
        for (int g=0; g<8; g++){
            uint4 hc = hp4[24+g];
            uint4 w0 = ws[j0][g ^ p0];
            uint4 w1 = ws[j1][g ^ p1];
            a0=dot2bf(w0.x,hc.x,a0); a1=dot2bf(w1.x,hc.x,a1);
            a2=dot2bf(w0.y,hc.y,a2); a3=dot2bf(w1.y,hc.y,a3);
            a0=dot2bf(w0.z,hc.z,a0); a1=dot2bf(w1.z,hc.z,a1);
            a2=dot2bf(w0.w,hc.w,a2); a3=dot2bf(w1.w,hc.w,a3);
        }
        if (tid >= 256){ zsf[tid-256] = a0+a2; zso[tid-256] = a1+a3; }
        __syncthreads();
        if (tid < 256){
            float i_ = zxv0 + a0+a2;
            float f_ = zxv1 + zsf[tid];
            float g_ = zxv2 + a1+a3;
            float o_ = zxv3 + zso[tid];
            float cn = fsig(f_)*c + fsig(i_)*ftanh(g_);
            c = cn;
            float hn = fsig(o_)*ftanh(cn);
            unsigned short hb = (unsigned short)f2b(hn);
            ((unsigned short*)hp4)[tid] = hb;
            hseq[row*256 + tid] = hb;
            if (outf) outf[row*256 + tid] = hn;
        }
        __syncthreads();
    }
    if (tid < 256){
        hfin[b*512 + fin_off + tid] = ((unsigned short*)hp4)[tid];
        cfin[b*512 + fin_off + tid] = c;
    }
}

// ---------------------------------------------------------------------------
// dot phase: thread computes 4 outputs (j=jq*4..+3) over ITERS k-pairs
// ---------------------------------------------------------------------------
template<int ITERS>
__device__ __forceinline__ void dot_phase(const unsigned* __restrict__ wbase,
    const unsigned* __restrict__ hu, int k2base, int jq, float* __restrict__ zrow)
{
    float a0=0.f,a1=0.f,a2=0.f,a3=0.f;
    const uint4* wp = (const uint4*)(wbase + (size_t)k2base*1024 + jq*4);
    #pragma unroll 8
    for (int kk=0; kk<ITERS; ++kk){
        uint4 w = wp[(size_t)kk*256];
        unsigned hp = hu[k2base+kk];
        a0=dot2bf(w.x,hp,a0); a1=dot2bf(w.y,hp,a1);
        a2=dot2bf(w.z,hp,a2); a3=dot2bf(w.w,hp,a3);
    }
    zrow[jq*4+0]=a0; zrow[jq*4+1]=a1; zrow[jq*4+2]=a2; zrow[jq*4+3]=a3;
}

// lstm prefetch chunk: runtime bounds, unroll 8
__device__ __forceinline__ void lch(int A, int B2, const uint4* __restrict__ wp,
    const unsigned* __restrict__ hu, float& a0, float& a1, float& a2, float& a3)
{
    #pragma unroll 8
    for (int k2=A; k2<B2; ++k2){
        uint4 w = wp[(size_t)k2*256];
        unsigned hp = hu[k2];
        a0=dot2bf(w.x,hp,a0); a1=dot2bf(w.y,hp,a1);
        a2=dot2bf(w.z,hp,a2); a3=dot2bf(w.w,hp,a3);
    }
}

// ---------------------------------------------------------------------------
// Decoder scan: 64 blocks (1/batch), 1024 threads (= 16 waves = 4/SIMD).
// __launch_bounds__(1024, 4): VGPR cap 128 (was 64 -> scratch spill, R7 lesson).
// Waves 0-7: attention pipeline.  Waves 8-15 (concurrently): stream+compute
// whh0@h1[t-1] and whh1@h2[t-1].  Then all: wx0@ctx -> pw0 -> wih1@h1 -> pw1+LN.
// ---------------------------------------------------------------------------
__global__ __launch_bounds__(1024, 4) void dec_scan(
    const float* __restrict__ embproj,
    const unsigned* __restrict__ wx0, const unsigned* __restrict__ whh0,
    const unsigned* __restrict__ wih1, const unsigned* __restrict__ whh1,
    const unsigned* __restrict__ pkWs,
    const float* __restrict__ b1d,
    const unsigned short* __restrict__ encp,  // [5120][256] bf16
    const unsigned short* __restrict__ enco,  // [5120][256] bf16 (= h2seq)
    const float* __restrict__ att_v, const float* __restrict__ M3,
    const float* __restrict__ attcb,
    const float* __restrict__ ln_g, const float* __restrict__ ln_b,
    const float* __restrict__ encfC, const unsigned short* __restrict__ encfH,
    unsigned short* __restrict__ normedb)
{
    int b = blockIdx.x, tid = threadIdx.x;
    __shared__ unsigned short encpL[SS*256];   // 40KB
    __shared__ unsigned short encoL[SS*256];   // 40KB
    __shared__ unsigned short h1b[256], h2b[256], ctxb[256];
    __shared__ float c1s[256], c2s[256];
    __shared__ float zb[4][1024];
    __shared__ float zbA[1024], zbB[1024];
    __shared__ float epL[1024];
    __shared__ float covs[82], scs[80], attns[80], dps[256];
    __shared__ float red[16];
    {
        const uint4* sp = (const uint4*)(encp + (size_t)b*SS*256);
        const uint4* so = (const uint4*)(enco + (size_t)b*SS*256);
        uint4* dp = (uint4*)encpL;
        uint4* dq = (uint4*)encoL;
        for (int i=tid; i<SS*256/8; i+=1024){ dp[i] = sp[i]; dq[i] = so[i]; }
    }
    int h = tid & 255;
    float bz0=0.f,bz1=0.f,bz2=0.f,bz3=0.f, gg=0.f, bb2=0.f;
    if (tid < 256){
        h1b[tid] = encfH[b*512 + tid];
        h2b[tid] = encfH[b*512 + 256 + tid];
        c1s[tid] = encfC[b*512 + tid];
        c2s[tid] = encfC[b*512 + 256 + tid];
        bz0=b1d[tid]; bz1=b1d[tid+256]; bz2=b1d[tid+512]; bz3=b1d[tid+768];
        gg=ln_g[tid]; bb2=ln_b[tid];
    }
    if (tid < 82) covs[tid] = 0.f;
    int wv = tid >> 6, lane = tid & 63;
    float va[4], m30[4], m31[4], m32[4];
    #pragma unroll
    for (int i=0;i<4;i++){
        int hh = lane + i*64;
        va[i]=att_v[hh]; m30[i]=M3[hh*3]; m31[i]=M3[hh*3+1]; m32[i]=M3[hh*3+2];
    }
    const unsigned* h1u = (const unsigned*)h1b;
    const unsigned* h2u = (const unsigned*)h2b;
    const unsigned* cxu = (const unsigned*)ctxb;
    // role split
    int hi  = tid >> 9;                 // 0: attention waves, 1: lstm-prefetch waves
    int q   = (tid >> 8) & 1;           // low-group 2-way split index
    int ljq = tid & 255;                // high-group output quad
    int lm  = (tid >> 8) & 1;           // high-group matrix select
    const uint4* lwp = (const uint4*)(lm ? whh1 : whh0) + ljq;
    const unsigned* lhu = lm ? h2u : h1u;
    float* lzb = lm ? zbB : zbA;
    __syncthreads();
    for (int t=0; t<TT; ++t){
        float la0=0.f,la1=0.f,la2=0.f,la3=0.f;
        // ---- overlapped region: attention (low) || whh0/whh1 stream (high) ----
        // chunk 0: dec_proj partials | lstm 0..25
        if (hi) lch(0, 26, lwp, lhu, la0,la1,la2,la3);
        else {
            float acc = 0.f;
            const unsigned* wp = pkWs + (size_t)(q*64)*256 + h;
            #pragma unroll 8
            for (int kk=0; kk<64; ++kk)
                acc = dot2bf(wp[(size_t)kk*256], h2u[q*64+kk], acc);
            zb[q][h] = acc;
        }
        __syncthreads();
        // chunk 1: dps reduce + embproj->LDS | lstm 26..51
        if (hi) lch(26, 52, lwp, lhu, la0,la1,la2,la3);
        else if (tid < 256) dps[tid] = attcb[tid] + zb[0][tid] + zb[1][tid];
        else {
            const float* er = embproj + ((size_t)b*TT + t)*1024;
            int i2 = tid - 256;
            epL[i2]     = er[i2];
            epL[i2+256] = er[i2+256];
            epL[i2+512] = er[i2+512];
            epL[i2+768] = er[i2+768];
        }
        __syncthreads();
        // chunk 2: scores | lstm 52..77
        if (hi) lch(52, 78, lwp, lhu, la0,la1,la2,la3);
        else {
            for (int s = wv*10; s < wv*10+10; ++s){
                float c0=covs[s], c1v=covs[s+1], c2v=covs[s+2];
                float p = 0.f;
                #pragma unroll
                for (int i=0;i<4;i++){
                    int hh = lane + i*64;
                    float e = b2f(encpL[s*256+hh]) + dps[hh]
                            + m30[i]*c0 + m31[i]*c1v + m32[i]*c2v;
                    p += va[i]*ftanh(e);
                }
                #pragma unroll
                for (int off=32;off;off>>=1) p += __shfl_down(p, off);
                if (lane == 0) scs[s] = p;
            }
        }
        __syncthreads();
        // chunk 3: softmax | lstm 78..103
        if (hi) lch(78, 104, lwp, lhu, la0,la1,la2,la3);
        else if (tid < 64){
            float a = scs[tid];
            float bsc = (tid < 16) ? scs[tid+64] : -3.4e38f;
            float mx = fmaxf(a, bsc);
            #pragma unroll
            for (int off=32;off;off>>=1) mx = fmaxf(mx, __shfl_xor(mx, off));
            float ea = __expf(a - mx);
            float eb = (tid < 16) ? __expf(bsc - mx) : 0.f;
            float sum = ea + eb;
            #pragma unroll
            for (int off=32;off;off>>=1) sum += __shfl_xor(sum, off);
            float inv = 1.f/sum;
            attns[tid] = ea*inv;
            if (tid < 16) attns[tid+64] = eb*inv;
        }
        __syncthreads();
        // chunk 4: cov update + ctx partials | lstm 104..127 + store partials
        if (hi){
            lch(104, 128, lwp, lhu, la0,la1,la2,la3);
            lzb[ljq*4+0]=la0; lzb[ljq*4+1]=la1; lzb[ljq*4+2]=la2; lzb[ljq*4+3]=la3;
        } else {
            if (tid < 80) covs[tid+1] += attns[tid];
            float acc = 0.f;
            for (int s=q*40; s<q*40+40; ++s)
                acc += attns[s]*b2f(encoL[s*256 + h]);
            zb[q][h] = acc;
        }
        __syncthreads();
        if (tid < 256)
            ctxb[h] = (unsigned short)f2b(zb[0][h] + zb[1][h]);
        __syncthreads();
        // ---- lstm0 sequential part: wx0 @ ctx (4-way k-split) ----
        dot_phase<32>(wx0, cxu, (tid>>8)*32, tid&255, &zb[tid>>8][0]);
        __syncthreads();
        if (tid < 256){
            float i_ = epL[h]     + zb[0][h]+zb[1][h]+zb[2][h]+zb[3][h] + zbA[h];
            float f_ = epL[h+256] + zb[0][h+256]+zb[1][h+256]+zb[2][h+256]+zb[3][h+256] + zbA[h+256];
            float g_ = epL[h+512] + zb[0][h+512]+zb[1][h+512]+zb[2][h+512]+zb[3][h+512] + zbA[h+512];
            float o_ = epL[h+768] + zb[0][h+768]+zb[1][h+768]+zb[2][h+768]+zb[3][h+768] + zbA[h+768];
            float cn = fsig(f_)*c1s[h] + fsig(i_)*ftanh(g_);
            c1s[h] = cn;
            h1b[h] = (unsigned short)f2b(fsig(o_)*ftanh(cn));
        }
        __syncthreads();
        // ---- lstm1 sequential part: wih1 @ h1[t] (4-way k-split) ----
        dot_phase<32>(wih1, h1u, (tid>>8)*32, tid&255, &zb[tid>>8][0]);
        __syncthreads();
        float hn = 0.f;
        if (tid < 256){
            float i_ = bz0 + zb[0][h]+zb[1][h]+zb[2][h]+zb[3][h] + zbB[h];
            float f_ = bz1 + zb[0][h+256]+zb[1][h+256]+zb[2][h+256]+zb[3][h+256] + zbB[h+256];
            float g_ = bz2 + zb[0][h+512]+zb[1][h+512]+zb[2][h+512]+zb[3][h+512] + zbB[h+512];
            float o_ = bz3 + zb[0][h+768]+zb[1][h+768]+zb[2][h+768]+zb[3][h+768] + zbB[h+768];
            float cn = fsig(f_)*c2s[h] + fsig(i_)*ftanh(g_);
            c2s[h] = cn;
            hn = fsig(o_)*ftanh(cn);
            h2b[h] = (unsigned short)f2b(hn);
        }
        // fused LayerNorm over h2
        float s1 = hn;
        #pragma unroll
        for (int off=32;off;off>>=1) s1 += __shfl_xor(s1, off);
        if (lane == 0) red[wv] = s1;
        __syncthreads();
        float mean = (red[0]+red[1]+red[2]+red[3]) * (1.f/256.f);
        __syncthreads();
        float d = (tid < 256) ? (hn - mean) : 0.f;
        float s2 = d*d;
        #pragma unroll
        for (int off=32;off;off>>=1) s2 += __shfl_xor(s2, off);
        if (lane == 0) red[wv] = s2;
        __syncthreads();
        float var = (red[0]+red[1]+red[2]+red[3]) * (1.f/256.f);
        if (tid < 256)
            normedb[((size_t)b*TT + t)*256 + h] =
                (unsigned short)f2b(d*rsqrtf(var + 1e-5f)*gg + bb2);
        __syncthreads();
    }
}

// ---------------------------------------------------------------------------
// Logits: bf16 MFMA, W-stationary. Block = 64 n-cols; loops all 80 m-tiles.
// ---------------------------------------------------------------------------
__global__ __launch_bounds__(256) void logits_mfma(
    const short* __restrict__ A, const short* __restrict__ Bw,
    const float* __restrict__ bias, float* __restrict__ out)
{
    int w = threadIdx.x >> 6, lane = threadIdx.x & 63;
    int n0 = blockIdx.x*64 + w*16;
    int row = lane & 15, kg = lane >> 4;
    bf16x8 bfr[8];
    const short* brow = Bw + (size_t)(n0 + row)*256 + kg*8;
    #pragma unroll
    for (int kk=0;kk<8;kk++) bfr[kk] = *reinterpret_cast<const bf16x8*>(brow + kk*32);
    float bv = bias[n0 + row];
    for (int mt=0; mt<80; ++mt){
        int m0 = mt*16;
        const short* arow = A + (size_t)(m0 + row)*256 + kg*8;
        f32x4 acc = {};
        #pragma unroll
        for (int kk=0;kk<8;kk++){
            bf16x8 a = *reinterpret_cast<const bf16x8*>(arow + kk*32);
            acc = __builtin_amdgcn_mfma_f32_16x16x32_bf16(a, bfr[kk], acc, 0, 0, 0);
        }
        #pragma unroll
        for (int r=0;r<4;r++){
            int m = m0 + kg*4 + r;
            out[(size_t)m*VV + n0 + row] = acc[r] + bv;
        }
    }
}

// ---------------------------------------------------------------------------
extern "C" void kernel_launch(void* const* d_in, const int* in_sizes, int n_in,
                              void* d_out, int out_size, void* d_ws, size_t ws_size,
                              hipStream_t stream)
{
    const float* video  = (const float*)d_in[0];
    const int*   caps   = (const int*)  d_in[1];
    const float* W_vp   = (const float*)d_in[2];
    const float* b_vp   = (const float*)d_in[3];
    const float* eWih0  = (const float*)d_in[4];
    const float* eWhh0  = (const float*)d_in[5];
    const float* e_bih0 = (const float*)d_in[6];
    const float* e_bhh0 = (const float*)d_in[7];
    const float* eWih1  = (const float*)d_in[8];
    const float* eWhh1  = (const float*)d_in[9];
    const float* e_bih1 = (const float*)d_in[10];
    const float* e_bhh1 = (const float*)d_in[11];
    const float* emb    = (const float*)d_in[12];
    const float* dWih0  = (const float*)d_in[13];
    const float* dWhh0  = (const float*)d_in[14];
    const float* d_bih0 = (const float*)d_in[15];
    const float* d_bhh0 = (const float*)d_in[16];
    const float* dWih1  = (const float*)d_in[17];
    const float* dWhh1  = (const float*)d_in[18];
    const float* d_bih1 = (const float*)d_in[19];
    const float* d_bhh1 = (const float*)d_in[20];
    const float* attWh  = (const float*)d_in[21];
    const float* attWs  = (const float*)d_in[22];
    const float* att_v  = (const float*)d_in[23];
    const float* attWc  = (const float*)d_in[24];
    const float* cov_w  = (const float*)d_in[25];
    const float* cov_b  = (const float*)d_in[26];
    const float* ln_g   = (const float*)d_in[27];
    const float* ln_b   = (const float*)d_in[28];
    const float* W_out  = (const float*)d_in[29];
    const float* b_out  = (const float*)d_in[30];
    float* out = (float*)d_out;

    float* W = (float*)d_ws;
    size_t o = 0;
    auto alloc = [&](size_t n){ size_t r = o; o += ((n + 63)/64)*64; return r; };

    // U region: vidb (bf16, 41.9MB) early, reused as z1x (fp32, 21MB) later
    float* U = W + alloc((size_t)10485760);
    unsigned short* vidb = (unsigned short*)U;
    float* z1x = U;
    float* zx0     = W + alloc((size_t)SS*BB*1024);     // fp32 [(b*80+t)*1024]
    float* embproj = W + alloc((size_t)TT*BB*1024);     // fp32 [(b*20+t)*1024]
    unsigned short* vp_b  = (unsigned short*)(W + alloc((size_t)SS*BB*HH/2));
    unsigned short* embg  = (unsigned short*)(W + alloc((size_t)TT*BB*HH/2));
    unsigned short* encpb = (unsigned short*)(W + alloc((size_t)BB*SS*HH/2));
    unsigned short* normedb = (unsigned short*)(W + alloc((size_t)BB*TT*HH/2));
    unsigned short* h1seq = (unsigned short*)(W + alloc((size_t)SS*BB*HH/2));
    unsigned short* h2seq = (unsigned short*)(W + alloc((size_t)SS*BB*HH/2));
    float* encfC   = W + alloc(BB*512);
    unsigned short* encfH = (unsigned short*)(W + alloc(BB*256));
    unsigned* pkWhh0e = (unsigned*)(W + alloc(128*1024));
    unsigned* pkWhh1e = (unsigned*)(W + alloc(128*1024));
    unsigned* pkWx0d  = (unsigned*)(W + alloc(128*1024));
    unsigned* pkWhh0d = (unsigned*)(W + alloc(128*1024));
    unsigned* pkWih1d = (unsigned*)(W + alloc(128*1024));
    unsigned* pkWhh1d = (unsigned*)(W + alloc(128*1024));
    unsigned* pkWs    = (unsigned*)(W + alloc(128*256));
    float* M3      = W + alloc(768);
    float* attcb   = W + alloc(256);
    float* b0e     = W + alloc(1024);
    float* b1e     = W + alloc(1024);
    float* b0d     = W + alloc(1024);
    float* b1d     = W + alloc(1024);
    unsigned short* Wob   = (unsigned short*)(W + alloc((size_t)VV*HH/2));
    unsigned short* Wib1  = (unsigned short*)(W + alloc(1024*HH/2));
    unsigned short* Whb   = (unsigned short*)(W + alloc(256*HH/2));
    unsigned short* Wvpb  = (unsigned short*)(W + alloc((size_t)HH*FF/2));
    unsigned short* Wih0b = (unsigned short*)(W + alloc(1024*HH/2));
    unsigned short* dWx0b = (unsigned short*)(W + alloc(1024*HH/2));
    (void)ws_size; (void)n_in; (void)in_sizes; (void)out_size;

    prep_kernel<<<17186, 256, 0, stream>>>(
        eWhh0, eWih1, eWhh1, dWih0, dWhh0, dWih1, dWhh1, attWs, attWc,
        cov_w, cov_b, e_bih0, e_bhh0, e_bih1, e_bhh1, d_bih0, d_bhh0, d_bih1, d_bhh1,
        W_out, attWh, W_vp, eWih0, video, emb, caps,
        pkWhh0e, pkWhh1e, pkWx0d, pkWhh0d, pkWih1d, pkWhh1d, pkWs,
        M3, attcb, b0e, b1e, b0d, b1d,
        Wob, Wib1, Whb, Wvpb, Wih0b, dWx0b, embg, vidb);

    // vp_b = bf16(video @ W_vp^T + b_vp)   (5120x256, K=4096)
    gemm_bf16<true><<<dim3(4, 80), 256, 0, stream>>>(
        FF, HH, (const short*)vidb, (const short*)Wvpb, b_vp, vp_b);

    // zx0 = vp_b @ eWih0^T + (bih0+bhh0)   (5120x1024, K=256) fp32
    gemm_bf16<false><<<dim3(16, 80), 256, 0, stream>>>(
        HH, 1024, (const short*)vp_b, (const short*)Wih0b, b0e, zx0);

    // embproj = embg @ dWih0[:, :256]^T + (bih0+bhh0)  (1280x1024, K=256) fp32
    gemm_bf16<false><<<dim3(16, 20), 256, 0, stream>>>(
        HH, 1024, (const short*)embg, (const short*)dWx0b, b0d, embproj);

    // encoder layer0 scan (weight-resident)
    lstm_scan<<<64, 512, 0, stream>>>(SS, zx0, pkWhh0e, h1seq, nullptr,
                                      encfH, encfC, 0);

    // z1x = h1seq @ Wih1^T + b1e  (5120x1024, K=256) fp32 (reuses U)
    gemm_bf16<false><<<dim3(16, 80), 256, 0, stream>>>(
        HH, 1024, (const short*)h1seq, (const short*)Wib1, b1e, z1x);

    // encoder layer1 scan; h2seq bf16 doubles as enco
    lstm_scan<<<64, 512, 0, stream>>>(SS, z1x, pkWhh1e, h2seq, nullptr,
                                      encfH, encfC, 256);

    // encp = bf16(h2seq @ attWh^T)  (5120x256, K=256)
    gemm_bf16<true><<<dim3(4, 80), 256, 0, stream>>>(
        HH, HH, (const short*)h2seq, (const short*)Whb, nullptr, encpb);

    // decoder scan (attention-overlapped weight streaming)
    dec_scan<<<64, 1024, 0, stream>>>(embproj, pkWx0d, pkWhh0d, pkWih1d, pkWhh1d,
                                      pkWs, b1d, encpb, h2seq, att_v, M3, attcb,
                                      ln_g, ln_b, encfC, encfH, normedb);

    // logits = normed @ W_out^T + b_out  (1280 x 32000, K=256)
    logits_mfma<<<VV/64, 256, 0, stream>>>(
        (const short*)normedb, (const short*)Wob, b_out, out);
}

// Round 9
// 1292.717 us; speedup vs baseline: 1.8421x; 1.8293x over previous
//
#include <hip/hip_runtime.h>
#include <math.h>

// Problem constants
#define BB 64
#define SS 80
#define TT 20
#define FF 4096
#define HH 256
#define VV 32000

typedef __attribute__((ext_vector_type(8))) short bf16x8;
typedef __attribute__((ext_vector_type(4))) float f32x4;

__device__ __forceinline__ float fsig(float x){ return 1.f/(1.f+__expf(-x)); }
__device__ __forceinline__ float ftanh(float x){
    float xc = fminf(fmaxf(x,-15.f),15.f);
    float e = __expf(2.f*xc);
    return (e-1.f)/(e+1.f);
}
__device__ __forceinline__ unsigned int f2b(float x){
    unsigned int u = __float_as_uint(x);
    return (u + 0x7fffu + ((u>>16)&1u)) >> 16;
}
__device__ __forceinline__ float b2f(unsigned short u){
    return __uint_as_float(((unsigned)u)<<16);
}
// acc += dot2(bf16pair w, bf16pair h)  -- CDNA v_dot2_f32_bf16
__device__ __forceinline__ float dot2bf(unsigned w, unsigned hp, float acc){
    float r;
    asm("v_dot2_f32_bf16 %0, %1, %2, %3" : "=v"(r) : "v"(w), "v"(hp), "v"(acc));
    return r;
}
__device__ __forceinline__ void pack8(const float* __restrict__ s, unsigned short* __restrict__ d){
    float4 a = *reinterpret_cast<const float4*>(s);
    float4 b = *reinterpret_cast<const float4*>(s+4);
    uint4 o;
    o.x = f2b(a.x) | (f2b(a.y)<<16);
    o.y = f2b(a.z) | (f2b(a.w)<<16);
    o.z = f2b(b.x) | (f2b(b.y)<<16);
    o.w = f2b(b.z) | (f2b(b.w)<<16);
    *reinterpret_cast<uint4*>(d) = o;
}

// ---------------------------------------------------------------------------
// prep: packed bf16 recurrence weights, M3, bias sums, and all bf16 converts
// pk layout: pk[k2*Nj + j] = bf16 W[j][2k2] | bf16 W[j][2k2+1]<<16
// ---------------------------------------------------------------------------
__global__ __launch_bounds__(256) void prep_kernel(
    const float* __restrict__ eWhh0, const float* __restrict__ eWih1, const float* __restrict__ eWhh1,
    const float* __restrict__ dWih0, const float* __restrict__ dWhh0, const float* __restrict__ dWih1,
    const float* __restrict__ dWhh1, const float* __restrict__ attWs, const float* __restrict__ attWc,
    const float* __restrict__ cov_w, const float* __restrict__ cov_b,
    const float* __restrict__ e_bih0, const float* __restrict__ e_bhh0,
    const float* __restrict__ e_bih1, const float* __restrict__ e_bhh1,
    const float* __restrict__ d_bih0, const float* __restrict__ d_bhh0,
    const float* __restrict__ d_bih1, const float* __restrict__ d_bhh1,
    const float* __restrict__ W_out, const float* __restrict__ attWh,
    const float* __restrict__ W_vp,  const float* __restrict__ eWih0,
    const float* __restrict__ video, const float* __restrict__ emb,
    const int*   __restrict__ captions,
    unsigned* pkWhh0e, unsigned* pkWhh1e, unsigned* pkWx0d,
    unsigned* pkWhh0d, unsigned* pkWih1d, unsigned* pkWhh1d, unsigned* pkWs,
    float* M3, float* attcb,
    float* b0e, float* b1e, float* b0d, float* b1d,
    unsigned short* Wob, unsigned short* Wib1, unsigned short* Whb,
    unsigned short* Wvpb, unsigned short* Wih0b, unsigned short* dWx0b,
    unsigned short* embg, unsigned short* vidb)
{
    int blk = blockIdx.x, tid = threadIdx.x;
    if (blk < 1856){
        const float* src; int stride, coff, Nj, j0, k0; unsigned* dst;
        if (blk < 1792){
            int mat = blk >> 8, tl = blk & 255;
            switch(mat){
                case 0: src=eWhh0; stride=256; coff=0;   dst=pkWhh0e; break;
                case 1: src=eWhh1; stride=256; coff=0;   dst=pkWhh1e; break;
                case 2: src=dWih0; stride=512; coff=256; dst=pkWx0d;  break;  // ctx cols
                case 3: src=dWhh0; stride=256; coff=0;   dst=pkWhh0d; break;
                case 4: src=dWih1; stride=256; coff=0;   dst=pkWih1d; break;
                case 5: src=dWhh1; stride=256; coff=0;   dst=pkWhh1d; break;
                default: return;   // spare slot
            }
            Nj = 1024; j0 = (tl>>3)*32; k0 = (tl&7)*32;
        } else {
            int tl = blk - 1792;
            src=attWs; stride=256; coff=0; dst=pkWs;
            Nj = 256; j0 = (tl>>3)*32; k0 = (tl&7)*32;
        }
        __shared__ float t1[32][33];
        int r = tid >> 5, c = tid & 31;
        #pragma unroll
        for (int i=0;i<4;i++)
            t1[r+i*8][c] = src[(size_t)(j0+r+i*8)*stride + coff + k0 + c];
        __syncthreads();
        int k2l = tid >> 5, j = tid & 31;
        #pragma unroll
        for (int i=0;i<2;i++){
            int kq = k2l + i*8;
            dst[(size_t)(k0/2 + kq)*Nj + j0 + j] =
                f2b(t1[j][2*kq]) | (f2b(t1[j][2*kq+1])<<16);
        }
        return;
    }
    if (blk == 1856){
        float m0=0.f,m1=0.f,m2=0.f,cb=0.f;
        for (int c=0;c<64;c++){
            float w = attWc[tid*64+c];
            m0 += w*cov_w[c*3+0]; m1 += w*cov_w[c*3+1]; m2 += w*cov_w[c*3+2];
            cb += w*cov_b[c];
        }
        M3[tid*3+0]=m0; M3[tid*3+1]=m1; M3[tid*3+2]=m2; attcb[tid]=cb;
        return;
    }
    if (blk == 1857){
        for (int i=tid;i<1024;i+=256){
            b0e[i]=e_bih0[i]+e_bhh0[i]; b1e[i]=e_bih1[i]+e_bhh1[i];
            b0d[i]=d_bih0[i]+d_bhh0[i]; b1d[i]=d_bih1[i]+d_bhh1[i];
        }
        return;
    }
    // bf16 conversions, 2048 elems/block
    if (blk >= 6946){ size_t i=(size_t)(blk-6946)*2048 + tid*8; pack8(video+i, vidb+i); return; }
    if (blk >= 6786){ size_t i=(size_t)(blk-6786)*2048 + tid*8;
        int row = (int)(i>>8), col = (int)(i&255);
        pack8(emb + (size_t)captions[row]*256 + col, embg+i); return; }
    if (blk >= 6658){ size_t i=(size_t)(blk-6658)*2048 + tid*8;
        int j = (int)(i>>8), k = (int)(i&255);
        pack8(dWih0 + (size_t)j*512 + k, dWx0b+i); return; }
    if (blk >= 6530){ size_t i=(size_t)(blk-6530)*2048 + tid*8; pack8(eWih0+i, Wih0b+i); return; }
    if (blk >= 6018){ size_t i=(size_t)(blk-6018)*2048 + tid*8; pack8(W_vp+i, Wvpb+i); return; }
    if (blk >= 5986){ size_t i=(size_t)(blk-5986)*2048 + tid*8; pack8(attWh+i, Whb+i); return; }
    if (blk >= 5858){ size_t i=(size_t)(blk-5858)*2048 + tid*8; pack8(eWih1+i, Wib1+i); return; }
    { size_t i=(size_t)(blk-1858)*2048 + tid*8; pack8(W_out+i, Wob+i); }
}

// ---------------------------------------------------------------------------
// Generic bf16 MFMA GEMM: out[M,N] = A[M,K] @ B[N,K]^T (+bias)
// ---------------------------------------------------------------------------
template<bool OUTBF>
__global__ __launch_bounds__(256) void gemm_bf16(int K, int N,
    const short* __restrict__ A, const short* __restrict__ Bw,
    const float* __restrict__ bias, void* __restrict__ out)
{
    int w = threadIdx.x >> 6, lane = threadIdx.x & 63;
    int m0 = blockIdx.y*64 + w*16, n0 = blockIdx.x*64;
    int row = lane & 15, kg = lane >> 4;
    const short* arow = A + (size_t)(m0 + row)*K + kg*8;
    f32x4 acc[4] = {};
    for (int kk=0; kk<K; kk+=32){
        bf16x8 a = *reinterpret_cast<const bf16x8*>(arow + kk);
        #pragma unroll
        for (int f=0; f<4; ++f){
            bf16x8 bfr = *reinterpret_cast<const bf16x8*>(
                Bw + (size_t)(n0 + f*16 + row)*K + kk + kg*8);
            acc[f] = __builtin_amdgcn_mfma_f32_16x16x32_bf16(a, bfr, acc[f], 0, 0, 0);
        }
    }
    #pragma unroll
    for (int f=0; f<4; ++f){
        int n = n0 + f*16 + row;
        float bv = bias ? bias[n] : 0.f;
        #pragma unroll
        for (int r=0; r<4; ++r){
            int m = m0 + kg*4 + r;
            float v = acc[f][r] + bv;
            if (OUTBF) ((unsigned short*)out)[(size_t)m*N + n] = (unsigned short)f2b(v);
            else       ((float*)out)[(size_t)m*N + n] = v;
        }
    }
}

// ---------------------------------------------------------------------------
// Weight-resident LSTM scan (encoder layers). 64 blocks, 512 threads.
// ---------------------------------------------------------------------------
__global__ __launch_bounds__(512, 2) void lstm_scan(
    int nsteps,
    const float* __restrict__ zx,
    const unsigned* __restrict__ pk,
    unsigned short* __restrict__ hseq,
    float* __restrict__ outf,
    unsigned short* __restrict__ hfin,
    float* __restrict__ cfin,
    int fin_off)
{
    __shared__ uint4 ws[1024][8];        // 128KB swizzled weight slice
    __shared__ uint4 hp4[32];            // 256 bf16 h as 32 uint4
    __shared__ float zsf[256], zso[256];
    int b = blockIdx.x, tid = threadIdx.x;
    int j0 = tid, j1 = tid + 512;
    unsigned wv0[96], wv1[96];
    #pragma unroll
    for (int kk=0; kk<96; kk++){
        wv0[kk] = pk[(size_t)kk*1024 + j0];
        wv1[kk] = pk[(size_t)kk*1024 + j1];
    }
    unsigned* wsu = (unsigned*)ws;
    for (int i = tid; i < 32*1024; i += 512){
        int kk = i >> 10, j = i & 1023;
        wsu[j*32 + (((kk>>2) ^ (j&7))<<2) + (kk&3)] = pk[(size_t)(96+kk)*1024 + j];
    }
    float c = 0.f;
    if (tid < 128) ((unsigned*)hp4)[tid] = 0;
    __syncthreads();
    int p0 = j0 & 7, p1 = j1 & 7;
    for (int t=0; t<nsteps; ++t){
        size_t row = (size_t)b*nsteps + t;
        float zxv0=0.f, zxv1=0.f, zxv2=0.f, zxv3=0.f;
        if (tid < 256){
            const float* zr = zx + row*1024;
            zxv0=zr[tid]; zxv1=zr[tid+256]; zxv2=zr[tid+512]; zxv3=zr[tid+768];
        }
        float a0=0.f,a1=0.f,a2=0.f,a3=0.f;
        #pragma unroll
        for (int g=0; g<24; g++){
            uint4 hc = hp4[g];
            a0=dot2bf(wv0[4*g+0],hc.x,a0); a1=dot2bf(wv1[4*g+0],hc.x,a1);
            a2=dot2bf(wv0[4*g+1],hc.y,a2); a3=dot2bf(wv1[4*g+1],hc.y,a3);
            a0=dot2bf(wv0[4*g+2],hc.z,a0); a1=dot2bf(wv1[4*g+2],hc.z,a1);
            a2=dot2bf(wv0[4*g+3],hc.w,a2); a3=dot2bf(wv1[4*g+3],hc.w,a3);
        }
        #pragma unroll
        for (int g=0; g<8; g++){
            uint4 hc = hp4[24+g];
            uint4 w0 = ws[j0][g ^ p0];
            uint4 w1 = ws[j1][g ^ p1];
            a0=dot2bf(w0.x,hc.x,a0); a1=dot2bf(w1.x,hc.x,a1);
            a2=dot2bf(w0.y,hc.y,a2); a3=dot2bf(w1.y,hc.y,a3);
            a0=dot2bf(w0.z,hc.z,a0); a1=dot2bf(w1.z,hc.z,a1);
            a2=dot2bf(w0.w,hc.w,a2); a3=dot2bf(w1.w,hc.w,a3);
        }
        if (tid >= 256){ zsf[tid-256] = a0+a2; zso[tid-256] = a1+a3; }
        __syncthreads();
        if (tid < 256){
            float i_ = zxv0 + a0+a2;
            float f_ = zxv1 + zsf[tid];
            float g_ = zxv2 + a1+a3;
            float o_ = zxv3 + zso[tid];
            float cn = fsig(f_)*c + fsig(i_)*ftanh(g_);
            c = cn;
            float hn = fsig(o_)*ftanh(cn);
            unsigned short hb = (unsigned short)f2b(hn);
            ((unsigned short*)hp4)[tid] = hb;
            hseq[row*256 + tid] = hb;
            if (outf) outf[row*256 + tid] = hn;
        }
        __syncthreads();
    }
    if (tid < 256){
        hfin[b*512 + fin_off + tid] = ((unsigned short*)hp4)[tid];
        cfin[b*512 + fin_off + tid] = c;
    }
}

// ---------------------------------------------------------------------------
// dot phase: thread computes 4 outputs (j=jq*4..+3) over ITERS k-pairs
// ---------------------------------------------------------------------------
template<int ITERS>
__device__ __forceinline__ void dot_phase(const unsigned* __restrict__ wbase,
    const unsigned* __restrict__ hu, int k2base, int jq, float* __restrict__ zrow)
{
    float a0=0.f,a1=0.f,a2=0.f,a3=0.f;
    const uint4* wp = (const uint4*)(wbase + (size_t)k2base*1024 + jq*4);
    #pragma unroll 8
    for (int kk=0; kk<ITERS; ++kk){
        uint4 w = wp[(size_t)kk*256];
        unsigned hp = hu[k2base+kk];
        a0=dot2bf(w.x,hp,a0); a1=dot2bf(w.y,hp,a1);
        a2=dot2bf(w.z,hp,a2); a3=dot2bf(w.w,hp,a3);
    }
    zrow[jq*4+0]=a0; zrow[jq*4+1]=a1; zrow[jq*4+2]=a2; zrow[jq*4+3]=a3;
}

// lstm prefetch chunk: runtime bounds, unroll 8
__device__ __forceinline__ void lch(int A, int B2, const uint4* __restrict__ wp,
    const unsigned* __restrict__ hu, float& a0, float& a1, float& a2, float& a3)
{
    #pragma unroll 8
    for (int k2=A; k2<B2; ++k2){
        uint4 w = wp[(size_t)k2*256];
        unsigned hp = hu[k2];
        a0=dot2bf(w.x,hp,a0); a1=dot2bf(w.y,hp,a1);
        a2=dot2bf(w.z,hp,a2); a3=dot2bf(w.w,hp,a3);
    }
}

// ---------------------------------------------------------------------------
// Decoder scan: 64 blocks (1/batch), 512 threads (8 waves, __launch_bounds__(512,2)
// -> 256-VGPR budget like lstm_scan; avoids the 1024-thread 64-VGPR spill, R7/R8).
// Threads 0-255 (4 waves): attention. Threads 256-511 (4 waves): concurrently
// stream whh0@h1[t-1] (chunks 0-1) and whh1@h2[t-1] (chunks 2-3) -> zbA/zbB.
// Then all 512: wx0@ctx -> pw0 -> wih1@h1 -> pw1 + LN.
// ---------------------------------------------------------------------------
__global__ __launch_bounds__(512, 2) void dec_scan(
    const float* __restrict__ embproj,
    const unsigned* __restrict__ wx0, const unsigned* __restrict__ whh0,
    const unsigned* __restrict__ wih1, const unsigned* __restrict__ whh1,
    const unsigned* __restrict__ pkWs,
    const float* __restrict__ b1d,
    const unsigned short* __restrict__ encp,  // [5120][256] bf16
    const unsigned short* __restrict__ enco,  // [5120][256] bf16 (= h2seq)
    const float* __restrict__ att_v, const float* __restrict__ M3,
    const float* __restrict__ attcb,
    const float* __restrict__ ln_g, const float* __restrict__ ln_b,
    const float* __restrict__ encfC, const unsigned short* __restrict__ encfH,
    unsigned short* __restrict__ normedb)
{
    int b = blockIdx.x, tid = threadIdx.x;
    __shared__ unsigned short encpL[SS*256];   // 40KB
    __shared__ unsigned short encoL[SS*256];   // 40KB
    __shared__ unsigned short h1b[256], h2b[256], ctxb[256];
    __shared__ float c1s[256], c2s[256];
    __shared__ float zb[2][1024];
    __shared__ float zbA[1024], zbB[1024];
    __shared__ float epL[1024];
    __shared__ float covs[82], scs[80], attns[80], dps[256];
    __shared__ float red[4];
    {
        const uint4* sp = (const uint4*)(encp + (size_t)b*SS*256);
        const uint4* so = (const uint4*)(enco + (size_t)b*SS*256);
        uint4* dp = (uint4*)encpL;
        uint4* dq = (uint4*)encoL;
        for (int i=tid; i<SS*256/8; i+=512){ dp[i] = sp[i]; dq[i] = so[i]; }
    }
    int h = tid & 255;
    float bz0=0.f,bz1=0.f,bz2=0.f,bz3=0.f, gg=0.f, bb2=0.f;
    if (tid < 256){
        h1b[tid] = encfH[b*512 + tid];
        h2b[tid] = encfH[b*512 + 256 + tid];
        c1s[tid] = encfC[b*512 + tid];
        c2s[tid] = encfC[b*512 + 256 + tid];
        bz0=b1d[tid]; bz1=b1d[tid+256]; bz2=b1d[tid+512]; bz3=b1d[tid+768];
        gg=ln_g[tid]; bb2=ln_b[tid];
    }
    if (tid < 82) covs[tid] = 0.f;
    int wv = tid >> 6, lane = tid & 63;        // wv 0..3 for attention group
    float va[4], m30[4], m31[4], m32[4];
    if (tid < 256){
        #pragma unroll
        for (int i=0;i<4;i++){
            int hh = lane + i*64;
            va[i]=att_v[hh]; m30[i]=M3[hh*3]; m31[i]=M3[hh*3+1]; m32[i]=M3[hh*3+2];
        }
    }
    const unsigned* h1u = (const unsigned*)h1b;
    const unsigned* h2u = (const unsigned*)h2b;
    const unsigned* cxu = (const unsigned*)ctxb;
    int hi  = tid >> 8;                 // 0: attention group, 1: stream group
    int ljq = tid & 255;                // stream output quad
    const uint4* lwp0 = (const uint4*)whh0 + ljq;
    const uint4* lwp1 = (const uint4*)whh1 + ljq;
    __syncthreads();
    for (int t=0; t<TT; ++t){
        float la0=0.f,la1=0.f,la2=0.f,la3=0.f;
        // chunk 0: dec_proj (full 128 k2, no split) | whh0 k2 0..63
        if (hi){
            lch(0, 64, lwp0, h1u, la0,la1,la2,la3);
        } else {
            float acc = attcb[h];
            const unsigned* wp = pkWs + h;
            #pragma unroll 8
            for (int kk=0; kk<128; ++kk)
                acc = dot2bf(wp[(size_t)kk*256], h2u[kk], acc);
            dps[h] = acc;
        }
        __syncthreads();
        // chunk 1: scores | whh0 k2 64..127 -> zbA
        if (hi){
            lch(64, 128, lwp0, h1u, la0,la1,la2,la3);
            zbA[ljq*4+0]=la0; zbA[ljq*4+1]=la1; zbA[ljq*4+2]=la2; zbA[ljq*4+3]=la3;
            la0=la1=la2=la3=0.f;
        } else {
            for (int s = wv*20; s < wv*20+20; ++s){
                float c0=covs[s], c1v=covs[s+1], c2v=covs[s+2];
                float p = 0.f;
                #pragma unroll
                for (int i=0;i<4;i++){
                    int hh = lane + i*64;
                    float e = b2f(encpL[s*256+hh]) + dps[hh]
                            + m30[i]*c0 + m31[i]*c1v + m32[i]*c2v;
                    p += va[i]*ftanh(e);
                }
                #pragma unroll
                for (int off=32;off;off>>=1) p += __shfl_down(p, off);
                if (lane == 0) scs[s] = p;
            }
        }
        __syncthreads();
        // chunk 2: softmax (tid<64) + embproj->LDS (tid 64..255) | whh1 k2 0..63
        if (hi){
            lch(0, 64, lwp1, h2u, la0,la1,la2,la3);
        } else if (tid < 64){
            float a = scs[tid];
            float bsc = (tid < 16) ? scs[tid+64] : -3.4e38f;
            float mx = fmaxf(a, bsc);
            #pragma unroll
            for (int off=32;off;off>>=1) mx = fmaxf(mx, __shfl_xor(mx, off));
            float ea = __expf(a - mx);
            float eb = (tid < 16) ? __expf(bsc - mx) : 0.f;
            float sum = ea + eb;
            #pragma unroll
            for (int off=32;off;off>>=1) sum += __shfl_xor(sum, off);
            float inv = 1.f/sum;
            attns[tid] = ea*inv;
            if (tid < 16) attns[tid+64] = eb*inv;
        } else {
            const float* er = embproj + ((size_t)b*TT + t)*1024;
            for (int i = tid-64; i < 1024; i += 192) epL[i] = er[i];
        }
        __syncthreads();
        // chunk 3: cov update + ctx | whh1 k2 64..127 -> zbB
        if (hi){
            lch(64, 128, lwp1, h2u, la0,la1,la2,la3);
            zbB[ljq*4+0]=la0; zbB[ljq*4+1]=la1; zbB[ljq*4+2]=la2; zbB[ljq*4+3]=la3;
        } else {
            if (tid < 80) covs[tid+1] += attns[tid];
            float acc = 0.f;
            #pragma unroll 8
            for (int s=0; s<80; ++s)
                acc += attns[s]*b2f(encoL[s*256 + h]);
            zb[0][h] = acc;
        }
        __syncthreads();
        if (tid < 256)
            ctxb[h] = (unsigned short)f2b(zb[0][h]);
        __syncthreads();
        // ---- lstm0 sequential part: wx0 @ ctx (2-way k-split, all 512) ----
        dot_phase<64>(wx0, cxu, hi*64, ljq, &zb[hi][0]);
        __syncthreads();
        if (tid < 256){
            float i_ = epL[h]     + zb[0][h]    +zb[1][h]     + zbA[h];
            float f_ = epL[h+256] + zb[0][h+256]+zb[1][h+256] + zbA[h+256];
            float g_ = epL[h+512] + zb[0][h+512]+zb[1][h+512] + zbA[h+512];
            float o_ = epL[h+768] + zb[0][h+768]+zb[1][h+768] + zbA[h+768];
            float cn = fsig(f_)*c1s[h] + fsig(i_)*ftanh(g_);
            c1s[h] = cn;
            h1b[h] = (unsigned short)f2b(fsig(o_)*ftanh(cn));
        }
        __syncthreads();
        // ---- lstm1 sequential part: wih1 @ h1[t] (2-way k-split, all 512) ----
        dot_phase<64>(wih1, h1u, hi*64, ljq, &zb[hi][0]);
        __syncthreads();
        float hn = 0.f;
        if (tid < 256){
            float i_ = bz0 + zb[0][h]    +zb[1][h]     + zbB[h];
            float f_ = bz1 + zb[0][h+256]+zb[1][h+256] + zbB[h+256];
            float g_ = bz2 + zb[0][h+512]+zb[1][h+512] + zbB[h+512];
            float o_ = bz3 + zb[0][h+768]+zb[1][h+768] + zbB[h+768];
            float cn = fsig(f_)*c2s[h] + fsig(i_)*ftanh(g_);
            c2s[h] = cn;
            hn = fsig(o_)*ftanh(cn);
            h2b[h] = (unsigned short)f2b(hn);
        }
        // fused LayerNorm over h2 (threads 0..255 = waves 0..3)
        float s1 = hn;
        #pragma unroll
        for (int off=32;off;off>>=1) s1 += __shfl_xor(s1, off);
        if (tid < 256 && lane == 0) red[wv] = s1;
        __syncthreads();
        float mean = (red[0]+red[1]+red[2]+red[3]) * (1.f/256.f);
        __syncthreads();
        float d = (tid < 256) ? (hn - mean) : 0.f;
        float s2 = d*d;
        #pragma unroll
        for (int off=32;off;off>>=1) s2 += __shfl_xor(s2, off);
        if (tid < 256 && lane == 0) red[wv] = s2;
        __syncthreads();
        float var = (red[0]+red[1]+red[2]+red[3]) * (1.f/256.f);
        if (tid < 256)
            normedb[((size_t)b*TT + t)*256 + h] =
                (unsigned short)f2b(d*rsqrtf(var + 1e-5f)*gg + bb2);
        __syncthreads();
    }
}

// ---------------------------------------------------------------------------
// Logits: bf16 MFMA, W-stationary. Block = 64 n-cols; loops all 80 m-tiles.
// ---------------------------------------------------------------------------
__global__ __launch_bounds__(256) void logits_mfma(
    const short* __restrict__ A, const short* __restrict__ Bw,
    const float* __restrict__ bias, float* __restrict__ out)
{
    int w = threadIdx.x >> 6, lane = threadIdx.x & 63;
    int n0 = blockIdx.x*64 + w*16;
    int row = lane & 15, kg = lane >> 4;
    bf16x8 bfr[8];
    const short* brow = Bw + (size_t)(n0 + row)*256 + kg*8;
    #pragma unroll
    for (int kk=0;kk<8;kk++) bfr[kk] = *reinterpret_cast<const bf16x8*>(brow + kk*32);
    float bv = bias[n0 + row];
    for (int mt=0; mt<80; ++mt){
        int m0 = mt*16;
        const short* arow = A + (size_t)(m0 + row)*256 + kg*8;
        f32x4 acc = {};
        #pragma unroll
        for (int kk=0;kk<8;kk++){
            bf16x8 a = *reinterpret_cast<const bf16x8*>(arow + kk*32);
            acc = __builtin_amdgcn_mfma_f32_16x16x32_bf16(a, bfr[kk], acc, 0, 0, 0);
        }
        #pragma unroll
        for (int r=0;r<4;r++){
            int m = m0 + kg*4 + r;
            out[(size_t)m*VV + n0 + row] = acc[r] + bv;
        }
    }
}

// ---------------------------------------------------------------------------
extern "C" void kernel_launch(void* const* d_in, const int* in_sizes, int n_in,
                              void* d_out, int out_size, void* d_ws, size_t ws_size,
                              hipStream_t stream)
{
    const float* video  = (const float*)d_in[0];
    const int*   caps   = (const int*)  d_in[1];
    const float* W_vp   = (const float*)d_in[2];
    const float* b_vp   = (const float*)d_in[3];
    const float* eWih0  = (const float*)d_in[4];
    const float* eWhh0  = (const float*)d_in[5];
    const float* e_bih0 = (const float*)d_in[6];
    const float* e_bhh0 = (const float*)d_in[7];
    const float* eWih1  = (const float*)d_in[8];
    const float* eWhh1  = (const float*)d_in[9];
    const float* e_bih1 = (const float*)d_in[10];
    const float* e_bhh1 = (const float*)d_in[11];
    const float* emb    = (const float*)d_in[12];
    const float* dWih0  = (const float*)d_in[13];
    const float* dWhh0  = (const float*)d_in[14];
    const float* d_bih0 = (const float*)d_in[15];
    const float* d_bhh0 = (const float*)d_in[16];
    const float* dWih1  = (const float*)d_in[17];
    const float* dWhh1  = (const float*)d_in[18];
    const float* d_bih1 = (const float*)d_in[19];
    const float* d_bhh1 = (const float*)d_in[20];
    const float* attWh  = (const float*)d_in[21];
    const float* attWs  = (const float*)d_in[22];
    const float* att_v  = (const float*)d_in[23];
    const float* attWc  = (const float*)d_in[24];
    const float* cov_w  = (const float*)d_in[25];
    const float* cov_b  = (const float*)d_in[26];
    const float* ln_g   = (const float*)d_in[27];
    const float* ln_b   = (const float*)d_in[28];
    const float* W_out  = (const float*)d_in[29];
    const float* b_out  = (const float*)d_in[30];
    float* out = (float*)d_out;

    float* W = (float*)d_ws;
    size_t o = 0;
    auto alloc = [&](size_t n){ size_t r = o; o += ((n + 63)/64)*64; return r; };

    // U region: vidb (bf16, 41.9MB) early, reused as z1x (fp32, 21MB) later
    float* U = W + alloc((size_t)10485760);
    unsigned short* vidb = (unsigned short*)U;
    float* z1x = U;
    float* zx0     = W + alloc((size_t)SS*BB*1024);     // fp32 [(b*80+t)*1024]
    float* embproj = W + alloc((size_t)TT*BB*1024);     // fp32 [(b*20+t)*1024]
    unsigned short* vp_b  = (unsigned short*)(W + alloc((size_t)SS*BB*HH/2));
    unsigned short* embg  = (unsigned short*)(W + alloc((size_t)TT*BB*HH/2));
    unsigned short* encpb = (unsigned short*)(W + alloc((size_t)BB*SS*HH/2));
    unsigned short* normedb = (unsigned short*)(W + alloc((size_t)BB*TT*HH/2));
    unsigned short* h1seq = (unsigned short*)(W + alloc((size_t)SS*BB*HH/2));
    unsigned short* h2seq = (unsigned short*)(W + alloc((size_t)SS*BB*HH/2));
    float* encfC   = W + alloc(BB*512);
    unsigned short* encfH = (unsigned short*)(W + alloc(BB*256));
    unsigned* pkWhh0e = (unsigned*)(W + alloc(128*1024));
    unsigned* pkWhh1e = (unsigned*)(W + alloc(128*1024));
    unsigned* pkWx0d  = (unsigned*)(W + alloc(128*1024));
    unsigned* pkWhh0d = (unsigned*)(W + alloc(128*1024));
    unsigned* pkWih1d = (unsigned*)(W + alloc(128*1024));
    unsigned* pkWhh1d = (unsigned*)(W + alloc(128*1024));
    unsigned* pkWs    = (unsigned*)(W + alloc(128*256));
    float* M3      = W + alloc(768);
    float* attcb   = W + alloc(256);
    float* b0e     = W + alloc(1024);
    float* b1e     = W + alloc(1024);
    float* b0d     = W + alloc(1024);
    float* b1d     = W + alloc(1024);
    unsigned short* Wob   = (unsigned short*)(W + alloc((size_t)VV*HH/2));
    unsigned short* Wib1  = (unsigned short*)(W + alloc(1024*HH/2));
    unsigned short* Whb   = (unsigned short*)(W + alloc(256*HH/2));
    unsigned short* Wvpb  = (unsigned short*)(W + alloc((size_t)HH*FF/2));
    unsigned short* Wih0b = (unsigned short*)(W + alloc(1024*HH/2));
    unsigned short* dWx0b = (unsigned short*)(W + alloc(1024*HH/2));
    (void)ws_size; (void)n_in; (void)in_sizes; (void)out_size;

    prep_kernel<<<17186, 256, 0, stream>>>(
        eWhh0, eWih1, eWhh1, dWih0, dWhh0, dWih1, dWhh1, attWs, attWc,
        cov_w, cov_b, e_bih0, e_bhh0, e_bih1, e_bhh1, d_bih0, d_bhh0, d_bih1, d_bhh1,
        W_out, attWh, W_vp, eWih0, video, emb, caps,
        pkWhh0e, pkWhh1e, pkWx0d, pkWhh0d, pkWih1d, pkWhh1d, pkWs,
        M3, attcb, b0e, b1e, b0d, b1d,
        Wob, Wib1, Whb, Wvpb, Wih0b, dWx0b, embg, vidb);

    // vp_b = bf16(video @ W_vp^T + b_vp)   (5120x256, K=4096)
    gemm_bf16<true><<<dim3(4, 80), 256, 0, stream>>>(
        FF, HH, (const short*)vidb, (const short*)Wvpb, b_vp, vp_b);

    // zx0 = vp_b @ eWih0^T + (bih0+bhh0)   (5120x1024, K=256) fp32
    gemm_bf16<false><<<dim3(16, 80), 256, 0, stream>>>(
        HH, 1024, (const short*)vp_b, (const short*)Wih0b, b0e, zx0);

    // embproj = embg @ dWih0[:, :256]^T + (bih0+bhh0)  (1280x1024, K=256) fp32
    gemm_bf16<false><<<dim3(16, 20), 256, 0, stream>>>(
        HH, 1024, (const short*)embg, (const short*)dWx0b, b0d, embproj);

    // encoder layer0 scan (weight-resident)
    lstm_scan<<<64, 512, 0, stream>>>(SS, zx0, pkWhh0e, h1seq, nullptr,
                                      encfH, encfC, 0);

    // z1x = h1seq @ Wih1^T + b1e  (5120x1024, K=256) fp32 (reuses U)
    gemm_bf16<false><<<dim3(16, 80), 256, 0, stream>>>(
        HH, 1024, (const short*)h1seq, (const short*)Wib1, b1e, z1x);

    // encoder layer1 scan; h2seq bf16 doubles as enco
    lstm_scan<<<64, 512, 0, stream>>>(SS, z1x, pkWhh1e, h2seq, nullptr,
                                      encfH, encfC, 256);

    // encp = bf16(h2seq @ attWh^T)  (5120x256, K=256)
    gemm_bf16<true><<<dim3(4, 80), 256, 0, stream>>>(
        HH, HH, (const short*)h2seq, (const short*)Whb, nullptr, encpb);

    // decoder scan (512-thread wave-specialized overlap)
    dec_scan<<<64, 512, 0, stream>>>(embproj, pkWx0d, pkWhh0d, pkWih1d, pkWhh1d,
                                     pkWs, b1d, encpb, h2seq, att_v, M3, attcb,
                                     ln_g, ln_b, encfC, encfH, normedb);

    // logits = normed @ W_out^T + b_out  (1280 x 32000, K=256)
    logits_mfma<<<VV/64, 256, 0, stream>>>(
        (const short*)normedb, (const short*)Wob, b_out, out);
}

// Round 11
// 1099.989 us; speedup vs baseline: 2.1648x; 1.1752x over previous
//
#include <hip/hip_runtime.h>
#include <math.h>

// Problem constants
#define BB 64
#define SS 80
#define TT 20
#define FF 4096
#define HH 256
#define VV 32000

typedef __attribute__((ext_vector_type(8))) short bf16x8;
typedef __attribute__((ext_vector_type(4))) float f32x4;

__device__ __forceinline__ float fsig(float x){ return 1.f/(1.f+__expf(-x)); }
__device__ __forceinline__ float ftanh(float x){
    float xc = fminf(fmaxf(x,-15.f),15.f);
    float e = __expf(2.f*xc);
    return (e-1.f)/(e+1.f);
}
__device__ __forceinline__ unsigned int f2b(float x){
    unsigned int u = __float_as_uint(x);
    return (u + 0x7fffu + ((u>>16)&1u)) >> 16;
}
__device__ __forceinline__ float b2f(unsigned short u){
    return __uint_as_float(((unsigned)u)<<16);
}
// acc += dot2(bf16pair w, bf16pair h)  -- CDNA v_dot2_f32_bf16
__device__ __forceinline__ float dot2bf(unsigned w, unsigned hp, float acc){
    float r;
    asm("v_dot2_f32_bf16 %0, %1, %2, %3" : "=v"(r) : "v"(w), "v"(hp), "v"(acc));
    return r;
}
__device__ __forceinline__ void pack8(const float* __restrict__ s, unsigned short* __restrict__ d){
    float4 a = *reinterpret_cast<const float4*>(s);
    float4 b = *reinterpret_cast<const float4*>(s+4);
    uint4 o;
    o.x = f2b(a.x) | (f2b(a.y)<<16);
    o.y = f2b(a.z) | (f2b(a.w)<<16);
    o.z = f2b(b.x) | (f2b(b.y)<<16);
    o.w = f2b(b.z) | (f2b(b.w)<<16);
    *reinterpret_cast<uint4*>(d) = o;
}

// ---------------------------------------------------------------------------
// prep: 7 pk-packed bf16 recurrence/attention matrices, M3, bias sums, and all
// plain-bf16 conversions.  pk[k2*Nj + j] = bf16 W[j][2k2] | bf16 W[j][2k2+1]<<16
// ---------------------------------------------------------------------------
__global__ __launch_bounds__(256) void prep_kernel(
    const float* __restrict__ eWhh0, const float* __restrict__ eWih1, const float* __restrict__ eWhh1,
    const float* __restrict__ dWih0, const float* __restrict__ dWhh0, const float* __restrict__ dWih1,
    const float* __restrict__ dWhh1, const float* __restrict__ attWs, const float* __restrict__ attWc,
    const float* __restrict__ cov_w, const float* __restrict__ cov_b,
    const float* __restrict__ e_bih0, const float* __restrict__ e_bhh0,
    const float* __restrict__ e_bih1, const float* __restrict__ e_bhh1,
    const float* __restrict__ d_bih0, const float* __restrict__ d_bhh0,
    const float* __restrict__ d_bih1, const float* __restrict__ d_bhh1,
    const float* __restrict__ W_out, const float* __restrict__ attWh,
    const float* __restrict__ W_vp,  const float* __restrict__ eWih0,
    const float* __restrict__ video, const float* __restrict__ emb,
    const int*   __restrict__ captions,
    unsigned* pkWhh0e, unsigned* pkWhh1e, unsigned* pkWih1e,
    unsigned* pkWx0d, unsigned* pkWhh0d, unsigned* pkWih1d, unsigned* pkWhh1d,
    unsigned* pkWs,
    float* M3, float* attcb,
    float* b0e, float* b1e, float* b0d, float* b1d,
    unsigned short* Wob, unsigned short* Whb,
    unsigned short* Wvpb, unsigned short* Wih0b, unsigned short* dWx0b,
    unsigned short* embg, unsigned short* vidb)
{
    int blk = blockIdx.x, tid = threadIdx.x;
    if (blk < 1856){
        const float* src; int stride, coff, Nj, j0, k0; unsigned* dst;
        if (blk < 1792){
            int mat = blk >> 8, tl = blk & 255;
            switch(mat){
                case 0: src=eWhh0; stride=256; coff=0;   dst=pkWhh0e; break;
                case 1: src=eWhh1; stride=256; coff=0;   dst=pkWhh1e; break;
                case 2: src=eWih1; stride=256; coff=0;   dst=pkWih1e; break;
                case 3: src=dWih0; stride=512; coff=256; dst=pkWx0d;  break;  // ctx cols
                case 4: src=dWhh0; stride=256; coff=0;   dst=pkWhh0d; break;
                case 5: src=dWih1; stride=256; coff=0;   dst=pkWih1d; break;
                default:src=dWhh1; stride=256; coff=0;   dst=pkWhh1d; break;
            }
            Nj = 1024; j0 = (tl>>3)*32; k0 = (tl&7)*32;
        } else {
            int tl = blk - 1792;
            src=attWs; stride=256; coff=0; dst=pkWs;
            Nj = 256; j0 = (tl>>3)*32; k0 = (tl&7)*32;
        }
        __shared__ float t1[32][33];
        int r = tid >> 5, c = tid & 31;
        #pragma unroll
        for (int i=0;i<4;i++)
            t1[r+i*8][c] = src[(size_t)(j0+r+i*8)*stride + coff + k0 + c];
        __syncthreads();
        int k2l = tid >> 5, j = tid & 31;
        #pragma unroll
        for (int i=0;i<2;i++){
            int kq = k2l + i*8;
            dst[(size_t)(k0/2 + kq)*Nj + j0 + j] =
                f2b(t1[j][2*kq]) | (f2b(t1[j][2*kq+1])<<16);
        }
        return;
    }
    if (blk == 1856){
        float m0=0.f,m1=0.f,m2=0.f,cb=0.f;
        for (int c=0;c<64;c++){
            float w = attWc[tid*64+c];
            m0 += w*cov_w[c*3+0]; m1 += w*cov_w[c*3+1]; m2 += w*cov_w[c*3+2];
            cb += w*cov_b[c];
        }
        M3[tid*3+0]=m0; M3[tid*3+1]=m1; M3[tid*3+2]=m2; attcb[tid]=cb;
        return;
    }
    if (blk == 1857){
        for (int i=tid;i<1024;i+=256){
            b0e[i]=e_bih0[i]+e_bhh0[i]; b1e[i]=e_bih1[i]+e_bhh1[i];
            b0d[i]=d_bih0[i]+d_bhh0[i]; b1d[i]=d_bih1[i]+d_bhh1[i];
        }
        return;
    }
    // bf16 conversions, 2048 elems/block; base 1858
    if (blk >= 6818){ size_t i=(size_t)(blk-6818)*2048 + tid*8; pack8(video+i, vidb+i); return; }
    if (blk >= 6658){ size_t i=(size_t)(blk-6658)*2048 + tid*8;
        int row = (int)(i>>8), col = (int)(i&255);
        pack8(emb + (size_t)captions[row]*256 + col, embg+i); return; }
    if (blk >= 6530){ size_t i=(size_t)(blk-6530)*2048 + tid*8;
        int j = (int)(i>>8), k = (int)(i&255);
        pack8(dWih0 + (size_t)j*512 + k, dWx0b+i); return; }
    if (blk >= 6402){ size_t i=(size_t)(blk-6402)*2048 + tid*8; pack8(eWih0+i, Wih0b+i); return; }
    if (blk >= 5890){ size_t i=(size_t)(blk-5890)*2048 + tid*8; pack8(W_vp+i, Wvpb+i); return; }
    if (blk >= 5858){ size_t i=(size_t)(blk-5858)*2048 + tid*8; pack8(attWh+i, Whb+i); return; }
    { size_t i=(size_t)(blk-1858)*2048 + tid*8; pack8(W_out+i, Wob+i); }
}

// ---------------------------------------------------------------------------
// Generic bf16 MFMA GEMM: out[M,N] = A[M,K] @ B[N,K]^T (+bias)
// ---------------------------------------------------------------------------
template<bool OUTBF>
__global__ __launch_bounds__(256) void gemm_bf16(int K, int N,
    const short* __restrict__ A, const short* __restrict__ Bw,
    const float* __restrict__ bias, void* __restrict__ out)
{
    int w = threadIdx.x >> 6, lane = threadIdx.x & 63;
    int m0 = blockIdx.y*64 + w*16, n0 = blockIdx.x*64;
    int row = lane & 15, kg = lane >> 4;
    const short* arow = A + (size_t)(m0 + row)*K + kg*8;
    f32x4 acc[4] = {};
    for (int kk=0; kk<K; kk+=32){
        bf16x8 a = *reinterpret_cast<const bf16x8*>(arow + kk);
        #pragma unroll
        for (int f=0; f<4; ++f){
            bf16x8 bfr = *reinterpret_cast<const bf16x8*>(
                Bw + (size_t)(n0 + f*16 + row)*K + kk + kg*8);
            acc[f] = __builtin_amdgcn_mfma_f32_16x16x32_bf16(a, bfr, acc[f], 0, 0, 0);
        }
    }
    #pragma unroll
    for (int f=0; f<4; ++f){
        int n = n0 + f*16 + row;
        float bv = bias ? bias[n] : 0.f;
        #pragma unroll
        for (int r=0; r<4; ++r){
            int m = m0 + kg*4 + r;
            float v = acc[f][r] + bv;
            if (OUTBF) ((unsigned short*)out)[(size_t)m*N + n] = (unsigned short)f2b(v);
            else       ((float*)out)[(size_t)m*N + n] = v;
        }
    }
}

// Shared resident-weight dot macro (uses wv0, wv1, ws, hp4, j0, j1, p0, p1)
#define RES_DOTS(a0,a1,a2,a3)                                              \
    _Pragma("unroll")                                                      \
    for (int g=0; g<24; g++){                                              \
        uint4 hc = hp4[g];                                                 \
        a0=dot2bf(wv0[4*g+0],hc.x,a0); a1=dot2bf(wv1[4*g+0],hc.x,a1);      \
        a2=dot2bf(wv0[4*g+1],hc.y,a2); a3=dot2bf(wv1[4*g+1],hc.y,a3);      \
        a0=dot2bf(wv0[4*g+2],hc.z,a0); a1=dot2bf(wv1[4*g+2],hc.z,a1);      \
        a2=dot2bf(wv0[4*g+3],hc.w,a2); a3=dot2bf(wv1[4*g+3],hc.w,a3);      \
    }                                                                      \
    _Pragma("unroll")                                                      \
    for (int g=0; g<8; g++){                                               \
        uint4 hc = hp4[24+g];                                              \
        uint4 w0 = ws[j0][g ^ p0];                                         \
        uint4 w1 = ws[j1][g ^ p1];                                         \
        a0=dot2bf(w0.x,hc.x,a0); a1=dot2bf(w1.x,hc.x,a1);                  \
        a2=dot2bf(w0.y,hc.y,a2); a3=dot2bf(w1.y,hc.y,a3);                  \
        a0=dot2bf(w0.z,hc.z,a0); a1=dot2bf(w1.z,hc.z,a1);                  \
        a2=dot2bf(w0.w,hc.w,a2); a3=dot2bf(w1.w,hc.w,a3);                  \
    }

// ---------------------------------------------------------------------------
// Pipelined encoder: 192 blocks x 512 threads, each stage weight-resident.
//   stage 0 (blk 0-63):    layer0 scan, publishes h1[t] (128 dwords bf16-pairs)
//   stage 1 (blk 64-127):  z1x[t] = Wih1 @ h1[t] + b1e, publishes 1024 floats
//   stage 2 (blk 128-191): layer1 scan consuming z1x[t]
// Handoff: device-scope RELAXED atomics (write-through to coherence point) +
// per-wave s_waitcnt vmcnt(0) before flag release.  NO __threadfence (avoids
// L2 writeback — round-3 lesson).  One-way flags; 192 blocks co-resident.
// ---------------------------------------------------------------------------
__global__ __launch_bounds__(512, 2) void enc_pipe(
    const float* __restrict__ zx0,
    const unsigned* __restrict__ pkWhh0, const unsigned* __restrict__ pkWih1,
    const unsigned* __restrict__ pkWhh1, const float* __restrict__ b1e,
    unsigned* __restrict__ h1pub,          // [b*80+t][128] dwords
    float* __restrict__ z1pub,             // [b*80+t][1024] fp32
    unsigned short* __restrict__ h2seq,    // [b*80+t][256] bf16
    unsigned short* __restrict__ hfin, float* __restrict__ cfin,
    unsigned* __restrict__ flagA, unsigned* __restrict__ flagB)
{
    __shared__ uint4 ws[1024][8];          // 128KB swizzled weight slice
    __shared__ uint4 hp4[32];              // 256 bf16 input vector
    __shared__ float zsf[256], zso[256];
    __shared__ float zsx[1024];            // stage2: z1x staging
    int gid = blockIdx.x, tid = threadIdx.x;
    int stage = gid >> 6, b = gid & 63;
    const unsigned* pk = (stage==0) ? pkWhh0 : ((stage==1) ? pkWih1 : pkWhh1);
    int j0 = tid, j1 = tid + 512;
    unsigned wv0[96], wv1[96];
    #pragma unroll
    for (int kk=0; kk<96; kk++){
        wv0[kk] = pk[(size_t)kk*1024 + j0];
        wv1[kk] = pk[(size_t)kk*1024 + j1];
    }
    unsigned* wsu = (unsigned*)ws;
    for (int i = tid; i < 32*1024; i += 512){
        int kk = i >> 10, j = i & 1023;
        wsu[j*32 + (((kk>>2) ^ (j&7))<<2) + (kk&3)] = pk[(size_t)(96+kk)*1024 + j];
    }
    int p0 = j0 & 7, p1 = j1 & 7;

    if (stage == 0){
        float c = 0.f;
        if (tid < 128) ((unsigned*)hp4)[tid] = 0;
        __syncthreads();
        for (int t=0; t<SS; ++t){
            size_t row = (size_t)b*SS + t;
            float zxv0=0.f, zxv1=0.f, zxv2=0.f, zxv3=0.f;
            if (tid < 256){
                const float* zr = zx0 + row*1024;
                zxv0=zr[tid]; zxv1=zr[tid+256]; zxv2=zr[tid+512]; zxv3=zr[tid+768];
            }
            float a0=0.f,a1=0.f,a2=0.f,a3=0.f;
            RES_DOTS(a0,a1,a2,a3)
            if (tid >= 256){ zsf[tid-256] = a0+a2; zso[tid-256] = a1+a3; }
            __syncthreads();
            if (tid < 256){
                float i_ = zxv0 + a0+a2;
                float f_ = zxv1 + zsf[tid];
                float g_ = zxv2 + a1+a3;
                float o_ = zxv3 + zso[tid];
                float cn = fsig(f_)*c + fsig(i_)*ftanh(g_);
                c = cn;
                ((unsigned short*)hp4)[tid] = (unsigned short)f2b(fsig(o_)*ftanh(cn));
            }
            __syncthreads();
            if (tid < 128)
                __hip_atomic_store(&h1pub[row*128 + tid], ((unsigned*)hp4)[tid],
                                   __ATOMIC_RELAXED, __HIP_MEMORY_SCOPE_AGENT);
            asm volatile("s_waitcnt vmcnt(0)" ::: "memory");
            __syncthreads();
            if (tid == 0)
                __hip_atomic_store(&flagA[b], (unsigned)(t+1),
                                   __ATOMIC_RELAXED, __HIP_MEMORY_SCOPE_AGENT);
        }
        if (tid < 256){
            hfin[b*512 + tid] = ((unsigned short*)hp4)[tid];
            cfin[b*512 + tid] = c;
        }
    } else if (stage == 1){
        float bj0 = b1e[j0], bj1 = b1e[j1];
        __syncthreads();
        for (int t=0; t<SS; ++t){
            size_t row = (size_t)b*SS + t;
            if (tid == 0){
                while (__hip_atomic_load(&flagA[b], __ATOMIC_RELAXED,
                                         __HIP_MEMORY_SCOPE_AGENT) < (unsigned)(t+1))
                    __builtin_amdgcn_s_sleep(2);
            }
            __syncthreads();
            if (tid < 128)
                ((unsigned*)hp4)[tid] = __hip_atomic_load(&h1pub[row*128 + tid],
                                          __ATOMIC_RELAXED, __HIP_MEMORY_SCOPE_AGENT);
            __syncthreads();
            float a0=0.f,a1=0.f,a2=0.f,a3=0.f;
            RES_DOTS(a0,a1,a2,a3)
            __hip_atomic_store(&z1pub[row*1024 + j0], a0+a2+bj0,
                               __ATOMIC_RELAXED, __HIP_MEMORY_SCOPE_AGENT);
            __hip_atomic_store(&z1pub[row*1024 + j1], a1+a3+bj1,
                               __ATOMIC_RELAXED, __HIP_MEMORY_SCOPE_AGENT);
            asm volatile("s_waitcnt vmcnt(0)" ::: "memory");
            __syncthreads();
            if (tid == 0)
                __hip_atomic_store(&flagB[b], (unsigned)(t+1),
                                   __ATOMIC_RELAXED, __HIP_MEMORY_SCOPE_AGENT);
        }
    } else {
        float c = 0.f;
        if (tid < 128) ((unsigned*)hp4)[tid] = 0;
        __syncthreads();
        for (int t=0; t<SS; ++t){
            size_t row = (size_t)b*SS + t;
            if (tid == 0){
                while (__hip_atomic_load(&flagB[b], __ATOMIC_RELAXED,
                                         __HIP_MEMORY_SCOPE_AGENT) < (unsigned)(t+1))
                    __builtin_amdgcn_s_sleep(2);
            }
            __syncthreads();
            zsx[j0] = __hip_atomic_load(&z1pub[row*1024 + j0],
                        __ATOMIC_RELAXED, __HIP_MEMORY_SCOPE_AGENT);
            zsx[j1] = __hip_atomic_load(&z1pub[row*1024 + j1],
                        __ATOMIC_RELAXED, __HIP_MEMORY_SCOPE_AGENT);
            float a0=0.f,a1=0.f,a2=0.f,a3=0.f;
            RES_DOTS(a0,a1,a2,a3)
            if (tid >= 256){ zsf[tid-256] = a0+a2; zso[tid-256] = a1+a3; }
            __syncthreads();
            if (tid < 256){
                float i_ = zsx[tid]     + a0+a2;
                float f_ = zsx[tid+256] + zsf[tid];
                float g_ = zsx[tid+512] + a1+a3;
                float o_ = zsx[tid+768] + zso[tid];
                float cn = fsig(f_)*c + fsig(i_)*ftanh(g_);
                c = cn;
                float hn = fsig(o_)*ftanh(cn);
                unsigned short hb = (unsigned short)f2b(hn);
                ((unsigned short*)hp4)[tid] = hb;
                h2seq[row*256 + tid] = hb;
            }
            __syncthreads();
        }
        if (tid < 256){
            hfin[b*512 + 256 + tid] = ((unsigned short*)hp4)[tid];
            cfin[b*512 + 256 + tid] = c;
        }
    }
}

// ---------------------------------------------------------------------------
// dot phase (decoder): thread computes 4 outputs (j=jq*4..+3) over ITERS k-pairs
// ---------------------------------------------------------------------------
template<int ITERS>
__device__ __forceinline__ void dot_phase(const unsigned* __restrict__ wbase,
    const unsigned* __restrict__ hu, int k2base, int jq, float* __restrict__ zrow)
{
    float a0=0.f,a1=0.f,a2=0.f,a3=0.f;
    const uint4* wp = (const uint4*)(wbase + (size_t)k2base*1024 + jq*4);
    #pragma unroll 8
    for (int kk=0; kk<ITERS; ++kk){
        uint4 w = wp[(size_t)kk*256];
        unsigned hp = hu[k2base+kk];
        a0=dot2bf(w.x,hp,a0); a1=dot2bf(w.y,hp,a1);
        a2=dot2bf(w.z,hp,a2); a3=dot2bf(w.w,hp,a3);
    }
    zrow[jq*4+0]=a0; zrow[jq*4+1]=a1; zrow[jq*4+2]=a2; zrow[jq*4+3]=a3;
}

// ---------------------------------------------------------------------------
// Decoder scan (round-6 proven version): 64 blocks (1/batch), 1024 threads.
// encp/enco staged in LDS once; per-step L2 stream = weights only. 482 µs.
// ---------------------------------------------------------------------------
__global__ __launch_bounds__(1024) void dec_scan(
    const float* __restrict__ embproj,
    const unsigned* __restrict__ wx0, const unsigned* __restrict__ whh0,
    const unsigned* __restrict__ wih1, const unsigned* __restrict__ whh1,
    const unsigned* __restrict__ pkWs,
    const float* __restrict__ b1d,
    const unsigned short* __restrict__ encp,
    const unsigned short* __restrict__ enco,
    const float* __restrict__ att_v, const float* __restrict__ M3,
    const float* __restrict__ attcb,
    const float* __restrict__ ln_g, const float* __restrict__ ln_b,
    const float* __restrict__ encfC, const unsigned short* __restrict__ encfH,
    unsigned short* __restrict__ normedb)
{
    int b = blockIdx.x, tid = threadIdx.x;
    __shared__ unsigned short encpL[SS*256];   // 40KB
    __shared__ unsigned short encoL[SS*256];   // 40KB
    __shared__ unsigned short h1b[256], h2b[256], ctxb[256];
    __shared__ float c1s[256], c2s[256];
    __shared__ float zb[4][1024];
    __shared__ float covs[82], scs[80], attns[80], dps[256];
    __shared__ float red[16];
    {
        const uint4* sp = (const uint4*)(encp + (size_t)b*SS*256);
        const uint4* so = (const uint4*)(enco + (size_t)b*SS*256);
        uint4* dp = (uint4*)encpL;
        uint4* dq = (uint4*)encoL;
        for (int i=tid; i<SS*256/8; i+=1024){ dp[i] = sp[i]; dq[i] = so[i]; }
    }
    int h = tid & 255;
    float bz0=0.f,bz1=0.f,bz2=0.f,bz3=0.f, gg=0.f, bb2=0.f;
    if (tid < 256){
        h1b[tid] = encfH[b*512 + tid];
        h2b[tid] = encfH[b*512 + 256 + tid];
        c1s[tid] = encfC[b*512 + tid];
        c2s[tid] = encfC[b*512 + 256 + tid];
        bz0=b1d[tid]; bz1=b1d[tid+256]; bz2=b1d[tid+512]; bz3=b1d[tid+768];
        gg=ln_g[tid]; bb2=ln_b[tid];
    }
    if (tid < 82) covs[tid] = 0.f;
    int wv = tid >> 6, lane = tid & 63;
    float va[4], m30[4], m31[4], m32[4];
    #pragma unroll
    for (int i=0;i<4;i++){
        int hh = lane + i*64;
        va[i]=att_v[hh]; m30[i]=M3[hh*3]; m31[i]=M3[hh*3+1]; m32[i]=M3[hh*3+2];
    }
    int q   = tid >> 8;        // 0..3
    int jq  = tid & 255;
    int m1  = tid >> 9;
    int ks1 = (tid >> 8) & 1;
    const unsigned* h1u = (const unsigned*)h1b;
    const unsigned* h2u = (const unsigned*)h2b;
    const unsigned* cxu = (const unsigned*)ctxb;
    __syncthreads();
    for (int t=0; t<TT; ++t){
        {   // dec_proj partials (bf16 dot2, k-split 4)
            float acc = 0.f;
            const unsigned* wp = pkWs + (size_t)(q*32)*256 + h;
            #pragma unroll 8
            for (int kk=0; kk<32; ++kk)
                acc = dot2bf(wp[(size_t)kk*256], h2u[q*32+kk], acc);
            zb[q][h] = acc;
        }
        __syncthreads();
        if (tid < 256) dps[tid] = attcb[tid] + zb[0][tid]+zb[1][tid]+zb[2][tid]+zb[3][tid];
        __syncthreads();
        for (int s = wv*5; s < wv*5+5; ++s){
            float c0=covs[s], c1v=covs[s+1], c2v=covs[s+2];
            float p = 0.f;
            #pragma unroll
            for (int i=0;i<4;i++){
                int hh = lane + i*64;
                float e = b2f(encpL[s*256+hh]) + dps[hh]
                        + m30[i]*c0 + m31[i]*c1v + m32[i]*c2v;
                p += va[i]*ftanh(e);
            }
            #pragma unroll
            for (int off=32;off;off>>=1) p += __shfl_down(p, off);
            if (lane == 0) scs[s] = p;
        }
        __syncthreads();
        if (tid < 64){
            float a = scs[tid];
            float bsc = (tid < 16) ? scs[tid+64] : -3.4e38f;
            float mx = fmaxf(a, bsc);
            #pragma unroll
            for (int off=32;off;off>>=1) mx = fmaxf(mx, __shfl_xor(mx, off));
            float ea = __expf(a - mx);
            float eb = (tid < 16) ? __expf(bsc - mx) : 0.f;
            float sum = ea + eb;
            #pragma unroll
            for (int off=32;off;off>>=1) sum += __shfl_xor(sum, off);
            float inv = 1.f/sum;
            attns[tid] = ea*inv;
            if (tid < 16) attns[tid+64] = eb*inv;
        }
        __syncthreads();
        if (tid < 80) covs[tid+1] += attns[tid];
        {   // ctx partials (s-split 4)
            float acc = 0.f;
            for (int s=q*20; s<q*20+20; ++s)
                acc += attns[s]*b2f(encoL[s*256 + h]);
            zb[q][h] = acc;
        }
        __syncthreads();
        if (tid < 256)
            ctxb[h] = (unsigned short)f2b(zb[0][h]+zb[1][h]+zb[2][h]+zb[3][h]);
        float ep0=0.f,ep1=0.f,ep2=0.f,ep3=0.f;
        if (tid < 256){
            const float* er = embproj + ((size_t)b*TT + t)*1024;
            ep0=er[h]; ep1=er[h+256]; ep2=er[h+512]; ep3=er[h+768];
        }
        __syncthreads();
        // ---- lstm0: x = ctx (wx0), h = h1 (whh0) ----
        dot_phase<64>(m1 ? whh0 : wx0, m1 ? h1u : cxu, ks1*64, jq, &zb[m1*2+ks1][0]);
        __syncthreads();
        if (tid < 256){
            float i_ = ep0+zb[0][h]+zb[1][h]+zb[2][h]+zb[3][h];
            float f_ = ep1+zb[0][h+256]+zb[1][h+256]+zb[2][h+256]+zb[3][h+256];
            float g_ = ep2+zb[0][h+512]+zb[1][h+512]+zb[2][h+512]+zb[3][h+512];
            float o_ = ep3+zb[0][h+768]+zb[1][h+768]+zb[2][h+768]+zb[3][h+768];
            float cn = fsig(f_)*c1s[h] + fsig(i_)*ftanh(g_);
            c1s[h] = cn;
            h1b[h] = (unsigned short)f2b(fsig(o_)*ftanh(cn));
        }
        __syncthreads();
        // ---- lstm1: x = h1 (wih1), h = h2 (whh1) ----
        dot_phase<64>(m1 ? whh1 : wih1, m1 ? h2u : h1u, ks1*64, jq, &zb[m1*2+ks1][0]);
        __syncthreads();
        float hn = 0.f;
        if (tid < 256){
            float i_ = bz0+zb[0][h]+zb[1][h]+zb[2][h]+zb[3][h];
            float f_ = bz1+zb[0][h+256]+zb[1][h+256]+zb[2][h+256]+zb[3][h+256];
            float g_ = bz2+zb[0][h+512]+zb[1][h+512]+zb[2][h+512]+zb[3][h+512];
            float o_ = bz3+zb[0][h+768]+zb[1][h+768]+zb[2][h+768]+zb[3][h+768];
            float cn = fsig(f_)*c2s[h] + fsig(i_)*ftanh(g_);
            c2s[h] = cn;
            hn = fsig(o_)*ftanh(cn);
            h2b[h] = (unsigned short)f2b(hn);
        }
        // fused LayerNorm over h2
        float s1 = hn;
        #pragma unroll
        for (int off=32;off;off>>=1) s1 += __shfl_xor(s1, off);
        if (lane == 0) red[wv] = s1;
        __syncthreads();
        float mean = (red[0]+red[1]+red[2]+red[3]) * (1.f/256.f);
        __syncthreads();
        float d = (tid < 256) ? (hn - mean) : 0.f;
        float s2 = d*d;
        #pragma unroll
        for (int off=32;off;off>>=1) s2 += __shfl_xor(s2, off);
        if (lane == 0) red[wv] = s2;
        __syncthreads();
        float var = (red[0]+red[1]+red[2]+red[3]) * (1.f/256.f);
        if (tid < 256)
            normedb[((size_t)b*TT + t)*256 + h] =
                (unsigned short)f2b(d*rsqrtf(var + 1e-5f)*gg + bb2);
        __syncthreads();
    }
}

// ---------------------------------------------------------------------------
// Logits: bf16 MFMA, W-stationary. Block = 64 n-cols; loops all 80 m-tiles.
// ---------------------------------------------------------------------------
__global__ __launch_bounds__(256) void logits_mfma(
    const short* __restrict__ A, const short* __restrict__ Bw,
    const float* __restrict__ bias, float* __restrict__ out)
{
    int w = threadIdx.x >> 6, lane = threadIdx.x & 63;
    int n0 = blockIdx.x*64 + w*16;
    int row = lane & 15, kg = lane >> 4;
    bf16x8 bfr[8];
    const short* brow = Bw + (size_t)(n0 + row)*256 + kg*8;
    #pragma unroll
    for (int kk=0;kk<8;kk++) bfr[kk] = *reinterpret_cast<const bf16x8*>(brow + kk*32);
    float bv = bias[n0 + row];
    for (int mt=0; mt<80; ++mt){
        int m0 = mt*16;
        const short* arow = A + (size_t)(m0 + row)*256 + kg*8;
        f32x4 acc = {};
        #pragma unroll
        for (int kk=0;kk<8;kk++){
            bf16x8 a = *reinterpret_cast<const bf16x8*>(arow + kk*32);
            acc = __builtin_amdgcn_mfma_f32_16x16x32_bf16(a, bfr[kk], acc, 0, 0, 0);
        }
        #pragma unroll
        for (int r=0;r<4;r++){
            int m = m0 + kg*4 + r;
            out[(size_t)m*VV + n0 + row] = acc[r] + bv;
        }
    }
}

// ---------------------------------------------------------------------------
extern "C" void kernel_launch(void* const* d_in, const int* in_sizes, int n_in,
                              void* d_out, int out_size, void* d_ws, size_t ws_size,
                              hipStream_t stream)
{
    const float* video  = (const float*)d_in[0];
    const int*   caps   = (const int*)  d_in[1];
    const float* W_vp   = (const float*)d_in[2];
    const float* b_vp   = (const float*)d_in[3];
    const float* eWih0  = (const float*)d_in[4];
    const float* eWhh0  = (const float*)d_in[5];
    const float* e_bih0 = (const float*)d_in[6];
    const float* e_bhh0 = (const float*)d_in[7];
    const float* eWih1  = (const float*)d_in[8];
    const float* eWhh1  = (const float*)d_in[9];
    const float* e_bih1 = (const float*)d_in[10];
    const float* e_bhh1 = (const float*)d_in[11];
    const float* emb    = (const float*)d_in[12];
    const float* dWih0  = (const float*)d_in[13];
    const float* dWhh0  = (const float*)d_in[14];
    const float* d_bih0 = (const float*)d_in[15];
    const float* d_bhh0 = (const float*)d_in[16];
    const float* dWih1  = (const float*)d_in[17];
    const float* dWhh1  = (const float*)d_in[18];
    const float* d_bih1 = (const float*)d_in[19];
    const float* d_bhh1 = (const float*)d_in[20];
    const float* attWh  = (const float*)d_in[21];
    const float* attWs  = (const float*)d_in[22];
    const float* att_v  = (const float*)d_in[23];
    const float* attWc  = (const float*)d_in[24];
    const float* cov_w  = (const float*)d_in[25];
    const float* cov_b  = (const float*)d_in[26];
    const float* ln_g   = (const float*)d_in[27];
    const float* ln_b   = (const float*)d_in[28];
    const float* W_out  = (const float*)d_in[29];
    const float* b_out  = (const float*)d_in[30];
    float* out = (float*)d_out;

    float* W = (float*)d_ws;
    size_t o = 0;
    auto alloc = [&](size_t n){ size_t r = o; o += ((n + 63)/64)*64; return r; };

    // U region: vidb (bf16, 41.9MB) early, reused as z1pub (fp32, 21MB) later
    float* U = W + alloc((size_t)10485760);
    unsigned short* vidb = (unsigned short*)U;
    float* z1pub = U;
    float* zx0     = W + alloc((size_t)SS*BB*1024);
    float* embproj = W + alloc((size_t)TT*BB*1024);
    unsigned short* vp_b  = (unsigned short*)(W + alloc((size_t)SS*BB*HH/2));
    unsigned short* embg  = (unsigned short*)(W + alloc((size_t)TT*BB*HH/2));
    unsigned short* encpb = (unsigned short*)(W + alloc((size_t)BB*SS*HH/2));
    unsigned short* normedb = (unsigned short*)(W + alloc((size_t)BB*TT*HH/2));
    unsigned* h1pub = (unsigned*)(W + alloc((size_t)SS*BB*128));
    unsigned short* h2seq = (unsigned short*)(W + alloc((size_t)SS*BB*HH/2));
    float* encfC   = W + alloc(BB*512);
    unsigned short* encfH = (unsigned short*)(W + alloc(BB*256));
    unsigned* flags = (unsigned*)(W + alloc(128));   // flagA[64] | flagB[64]
    unsigned* pkWhh0e = (unsigned*)(W + alloc(128*1024));
    unsigned* pkWhh1e = (unsigned*)(W + alloc(128*1024));
    unsigned* pkWih1e = (unsigned*)(W + alloc(128*1024));
    unsigned* pkWx0d  = (unsigned*)(W + alloc(128*1024));
    unsigned* pkWhh0d = (unsigned*)(W + alloc(128*1024));
    unsigned* pkWih1d = (unsigned*)(W + alloc(128*1024));
    unsigned* pkWhh1d = (unsigned*)(W + alloc(128*1024));
    unsigned* pkWs    = (unsigned*)(W + alloc(128*256));
    float* M3      = W + alloc(768);
    float* attcb   = W + alloc(256);
    float* b0e     = W + alloc(1024);
    float* b1e     = W + alloc(1024);
    float* b0d     = W + alloc(1024);
    float* b1d     = W + alloc(1024);
    unsigned short* Wob   = (unsigned short*)(W + alloc((size_t)VV*HH/2));
    unsigned short* Whb   = (unsigned short*)(W + alloc(256*HH/2));
    unsigned short* Wvpb  = (unsigned short*)(W + alloc((size_t)HH*FF/2));
    unsigned short* Wih0b = (unsigned short*)(W + alloc(1024*HH/2));
    unsigned short* dWx0b = (unsigned short*)(W + alloc(1024*HH/2));
    (void)ws_size; (void)n_in; (void)in_sizes; (void)out_size;

    hipMemsetAsync(flags, 0, 128*sizeof(unsigned), stream);

    prep_kernel<<<17058, 256, 0, stream>>>(
        eWhh0, eWih1, eWhh1, dWih0, dWhh0, dWih1, dWhh1, attWs, attWc,
        cov_w, cov_b, e_bih0, e_bhh0, e_bih1, e_bhh1, d_bih0, d_bhh0, d_bih1, d_bhh1,
        W_out, attWh, W_vp, eWih0, video, emb, caps,
        pkWhh0e, pkWhh1e, pkWih1e, pkWx0d, pkWhh0d, pkWih1d, pkWhh1d, pkWs,
        M3, attcb, b0e, b1e, b0d, b1d,
        Wob, Whb, Wvpb, Wih0b, dWx0b, embg, vidb);

    // vp_b = bf16(video @ W_vp^T + b_vp)   (5120x256, K=4096)
    gemm_bf16<true><<<dim3(4, 80), 256, 0, stream>>>(
        FF, HH, (const short*)vidb, (const short*)Wvpb, b_vp, vp_b);

    // zx0 = vp_b @ eWih0^T + (bih0+bhh0)   (5120x1024, K=256) fp32
    gemm_bf16<false><<<dim3(16, 80), 256, 0, stream>>>(
        HH, 1024, (const short*)vp_b, (const short*)Wih0b, b0e, zx0);

    // embproj = embg @ dWih0[:, :256]^T + (bih0+bhh0)  (1280x1024, K=256) fp32
    gemm_bf16<false><<<dim3(16, 20), 256, 0, stream>>>(
        HH, 1024, (const short*)embg, (const short*)dWx0b, b0d, embproj);

    // pipelined encoder: layer0 || z1x || layer1 (192 blocks, fence-free flags)
    enc_pipe<<<192, 512, 0, stream>>>(zx0, pkWhh0e, pkWih1e, pkWhh1e, b1e,
                                      h1pub, z1pub, h2seq, encfH, encfC,
                                      flags, flags + 64);

    // encp = bf16(h2seq @ attWh^T)  (5120x256, K=256)
    gemm_bf16<true><<<dim3(4, 80), 256, 0, stream>>>(
        HH, HH, (const short*)h2seq, (const short*)Whb, nullptr, encpb);

    // decoder scan (round-6 proven version)
    dec_scan<<<64, 1024, 0, stream>>>(embproj, pkWx0d, pkWhh0d, pkWih1d, pkWhh1d,
                                      pkWs, b1d, encpb, h2seq, att_v, M3, attcb,
                                      ln_g, ln_b, encfC, encfH, normedb);

    // logits = normed @ W_out^T + b_out  (1280 x 32000, K=256)
    logits_mfma<<<VV/64, 256, 0, stream>>>(
        (const short*)normedb, (const short*)Wob, b_out, out);
}